// Round 9
// baseline (1422.113 us; speedup 1.0000x reference)
//
#include <hip/hip_runtime.h>

// ---------------------------------------------------------------------------
// OGRENet GraphNet block — f16 MFMA, BLOCKED operands.
// Blocked layout (f16): offset(m,k) = ((mt*KTo + kt)*4 + kg)*1024 + r*8 + ko
// R12: ew4+nw0 folded; R13: k_final folded into m0 (MODE=3).
// R18: EC=32768 full-fill WIN. R19: read-12-frags + 1 barrier/phase (74us).
// R20: WAR-prefetch into MFMA source regs REGRESSED (hazard). Reverted.
// R21: gemm256h — R19 schedule in 4-wave 256x128 blocks, 2 LDS regions,
//      2 blocks/CU, grid 8x128 = 2.00 rounds. WIN: 1381 us; wide no longer
//      top cost. New top: n1 scatter (gemm_blk<2>) 73us x4 — NOT compute/
//      HBM-bound (Mfma 8.6%, 1.17TB/s); paced by __syncthreads vmcnt(0)
//      draining in-flight atomics 8x per kernel.
// R22: lgkm-only barriers (s_waitcnt lgkmcnt(0); s_barrier) where only LDS
//      ordering is needed: MODE-2 pass barriers (atomics stream across
//      passes), MODE-0 + gemm256h + gemmAD epilogues. EXCEPTION: gemmAD's
//      FIRST epilogue barrier stays full __syncthreads — its tail leaves
//      <=12 gld_lds writes outstanding (vmcnt) into the LDS that tr
//      overlays. gemm256h exits with vmcnt=0 (last phase waits 0, stages
//      nothing) -> safe. Store-data reg reuse: compiler inserts counted
//      vmcnt waits (cheap vs full drain).
// [R8: template MODE; R10/R11: BK=64 + lb(256,4) -> VGPR 60, 4 blk/CU;
//  R7: rocprof replay overstates atomic kernels ~20x — trust timed totals.]
// ---------------------------------------------------------------------------

#define NN 20000
#define EE 100000
#define BB 16

typedef _Float16 f16x8 __attribute__((ext_vector_type(8)));
typedef _Float16 f16x4 __attribute__((ext_vector_type(4)));
typedef float f32x4 __attribute__((ext_vector_type(4)));

__device__ __forceinline__ int clampi(int v, int hi) {
    return v < 0 ? 0 : (v >= hi ? hi - 1 : v);
}

__device__ __forceinline__ void gld_lds16(const void* g, void* l) {
    __builtin_amdgcn_global_load_lds(
        (const __attribute__((address_space(1))) unsigned int*)g,
        (__attribute__((address_space(3))) unsigned int*)l, 16, 0, 0);
}

// barrier that orders LDS (lgkm) but lets VMEM stores/atomics stay in flight
__device__ __forceinline__ void bar_lgkm() {
    asm volatile("s_waitcnt lgkmcnt(0)" ::: "memory");
    __builtin_amdgcn_s_barrier();
}

// -------- 256x128-tile 4-wave GEMM, 2 regions, 2 blocks/CU (R21) -----------
// A blocked [2*MT2][KTs] (row pages 2p,2p+1), Wt blocked [8][KT] (128-col
// tiles), C blocked [2*MT2][KTo]. 4 waves: wm=wid&1 (row page), wn=wid>>1
// (64-col half). Per wave: 128x64 out, acc[8][4]. Phase s: vmcnt(0) ->
// barrier -> stage(s+1) -> 12 frag reads -> 32 MFMA (setprio).
__global__ __launch_bounds__(256, 2) void gemm256h(
    const _Float16* __restrict__ Ag, const _Float16* __restrict__ Wt,
    int KT, int KTs, const float* __restrict__ bias,
    _Float16* __restrict__ C, int KTo, int ktOff)
{
    __shared__ _Float16 smem[24576];   // 2 regions x (A 8192 + B 4096) f16

    const int tid  = threadIdx.x;
    const int lane = tid & 63;
    const int wid  = tid >> 6;       // 0..3
    const int wm   = wid & 1;        // row page (128 rows)
    const int wn   = wid >> 1;       // col half (64 cols)
    const int l15  = lane & 15;
    const int l4   = (lane >> 4) << 2;
    const int kq   = (lane >> 4) << 10;

    // XCD swizzle: panel p's column-blocks share f%8 (same XCD)
    const int nb  = gridDim.x;       // 8
    const int MT2 = gridDim.y;
    int f = blockIdx.y * nb + blockIdx.x;
    const int MT8 = MT2 & ~7;
    int p, c;
    if (f < MT8 * nb) {
        c = (f >> 3) % nb;
        p = (f & 7) + 8 * ((f >> 3) / nb);
    } else {
        int g = f - MT8 * nb;
        p = MT8 + g / nb;
        c = g % nb;
    }

    const int S = KT;                // phases; gemm256h only sees even S
    auto stage = [&](int ph) {
        const _Float16* gA0 = Ag + ((size_t)(2 * p)     * KTs + ph) * 4096 + tid * 8;
        const _Float16* gA1 = Ag + ((size_t)(2 * p + 1) * KTs + ph) * 4096 + tid * 8;
        const _Float16* gB  = Wt + ((size_t)c * KT + ph) * 4096 + tid * 8;
        _Float16* rA = smem + (ph & 1) * 12288;
        _Float16* rB = rA + 8192;
        gld_lds16(gA0,        rA + wid * 512);
        gld_lds16(gA0 + 2048, rA + 2048 + wid * 512);
        gld_lds16(gA1,        rA + 4096 + wid * 512);
        gld_lds16(gA1 + 2048, rA + 6144 + wid * 512);
        gld_lds16(gB,         rB + wid * 512);
        gld_lds16(gB + 2048,  rB + 2048 + wid * 512);
    };

    f32x4 acc[8][4];
#pragma unroll
    for (int i = 0; i < 8; ++i)
#pragma unroll
        for (int j = 0; j < 4; ++j) acc[i][j] = (f32x4){0.f, 0.f, 0.f, 0.f};

    stage(0);

    for (int s = 0; s < S; ++s) {
        asm volatile("s_waitcnt vmcnt(0)" ::: "memory");
        __builtin_amdgcn_s_barrier();
        if (s + 1 < S) stage(s + 1);
        const _Float16* rA = smem + (s & 1) * 12288;
        const _Float16* rB = rA + 8192;
        const _Float16* Ap = rA + wm * 4096 + kq + l15 * 8;
        const _Float16* Bp = rB + kq + wn * 512 + l15 * 8;
        f16x8 af[8], bf[4];
#pragma unroll
        for (int j = 0; j < 4; ++j) bf[j] = *(const f16x8*)(Bp + j * 128);
#pragma unroll
        for (int i = 0; i < 8; ++i) af[i] = *(const f16x8*)(Ap + i * 128);
        __builtin_amdgcn_s_setprio(1);
#pragma unroll
        for (int i = 0; i < 8; ++i)
#pragma unroll
            for (int j = 0; j < 4; ++j)
                acc[i][j] = __builtin_amdgcn_mfma_f32_16x16x32_f16(
                    af[i], bf[j], acc[i][j], 0, 0, 0);
        __builtin_amdgcn_s_setprio(0);
    }

    // epilogue: 4 passes of 64 rows; tr = [64][132] f16 (8448 f16 <= smem)
    // vm outstanding = 0 at loop exit (last phase waits vmcnt(0), stages
    // nothing) -> lgkm-only barriers are safe throughout.
    _Float16* tr = smem;
#pragma unroll
    for (int pass = 0; pass < 4; ++pass) {
        bar_lgkm();
        if (wm == (pass >> 1)) {
            const int fi = (pass & 1) << 2;
#pragma unroll
            for (int i = 0; i < 4; ++i) {
#pragma unroll
                for (int v = 0; v < 4; ++v) {
                    const int lr = i * 16 + l4 + v;
#pragma unroll
                    for (int j = 0; j < 4; ++j) {
                        const int cc = wn * 64 + j * 16 + l15;
                        float val = acc[fi + i][j][v] + bias[c * 128 + cc];
                        val = fmaxf(val, 0.f);
                        tr[lr * 132 + cc] = (_Float16)val;
                    }
                }
            }
        }
        bar_lgkm();
#pragma unroll
        for (int it = 0; it < 4; ++it) {
            const int id = it * 256 + tid;
            const int r  = id & 63;
            const int cg = id >> 6;        // 0..15 (128 cols)
            f16x4 lo = *(const f16x4*)(tr + r * 132 + cg * 8);
            f16x4 hi = *(const f16x4*)(tr + r * 132 + cg * 8 + 4);
            f16x8 v8;
#pragma unroll
            for (int t = 0; t < 4; ++t) { v8[t] = lo[t]; v8[t + 4] = hi[t]; }
            const int kti = ktOff + (c << 2) + (cg >> 2);
            const int mt_out = 2 * p + (pass >> 1);
            const int r128 = ((pass & 1) << 6) + r;
            *(f16x8*)(C + (((size_t)mt_out * KTo + kti) * 4 + (cg & 3)) * 1024
                        + (size_t)r128 * 8) = v8;
        }
    }
}

// ------------- 128x128 A-in-LDS-ring / B-direct GEMM (R16, verified) -------
// Odd-KT tail: pair loop covers bodies 0..KT-2; body(KT-2 pair end)
// preloads B(KT-1) into bfA; tail consumes bfA.
__global__ __launch_bounds__(256, 3) void gemmAD(
    const _Float16* __restrict__ Ag, const _Float16* __restrict__ Wt,
    int KT, int KTs, const float* __restrict__ bias,
    _Float16* __restrict__ C, int KTo, int ktOff)
{
    __shared__ _Float16 As[16384];   // 4-slot ring x 4096 f16 = 32 KB

    const int tid  = threadIdx.x;
    const int lane = tid & 63;
    const int wid  = tid >> 6;
    const int wm = (wid & 1) << 6;
    const int wn = (wid >> 1) << 6;
    const int l15 = lane & 15;
    const int l4  = (lane >> 4) << 2;
    const int kg  = (lane >> 4) << 10;

    const int nb = gridDim.x;
    const int MT = gridDim.y;
    int f = blockIdx.y * nb + blockIdx.x;
    const int MT8 = MT & ~7;
    int p, c;
    if (f < MT8 * nb) {
        c = (f >> 3) % nb;
        p = (f & 7) + 8 * ((f >> 3) / nb);
    } else {
        int g = f - MT8 * nb;
        p = MT8 + g / nb;
        c = g % nb;
    }

    f32x4 acc[4][4];
#pragma unroll
    for (int i = 0; i < 4; ++i)
#pragma unroll
        for (int j = 0; j < 4; ++j) acc[i][j] = (f32x4){0.f, 0.f, 0.f, 0.f};

    const _Float16* gA = Ag + (size_t)p * KTs * 4096;
    const _Float16* gB = Wt + ((size_t)c * KT) * 4096 + kg + (wn + l15) * 8;
    const int ktLim = KT - 1;

    auto stageA = [&](int ktA) {
        const _Float16* s = gA + (size_t)ktA * 4096 + tid * 8;
        _Float16* d = As + ((ktA & 3) << 12) + wid * 512;
        gld_lds16(s, d);
        gld_lds16(s + 2048, d + 2048);
    };

    f16x8 bfA[4], bfB[4];
    auto loadB = [&](f16x8 (&bf)[4], int ktB) {
        const _Float16* bp = gB + (size_t)ktB * 4096;
#pragma unroll
        for (int j = 0; j < 4; ++j) bf[j] = *(const f16x8*)(bp + j * 128);
    };

    stageA(0);
    stageA(1 <= ktLim ? 1 : ktLim);
    loadB(bfA, 0);

    auto body = [&](int kt, f16x8 (&cur)[4], f16x8 (&nxt)[4]) {
        const int ktB = kt + 1 <= ktLim ? kt + 1 : ktLim;
        const int ktA = kt + 2 <= ktLim ? kt + 2 : ktLim;
        loadB(nxt, ktB);
        stageA(ktA);
        asm volatile("s_waitcnt vmcnt(12)" ::: "memory");
        __builtin_amdgcn_s_barrier();
        asm volatile("" ::: "memory");
        const _Float16* Ap = As + ((kt & 3) << 12) + kg + (wm + l15) * 8;
        f16x8 af[4];
#pragma unroll
        for (int i = 0; i < 4; ++i) af[i] = *(const f16x8*)(Ap + i * 128);
        __builtin_amdgcn_s_setprio(1);
#pragma unroll
        for (int i = 0; i < 4; ++i)
#pragma unroll
            for (int j = 0; j < 4; ++j)
                acc[i][j] = __builtin_amdgcn_mfma_f32_16x16x32_f16(
                    af[i], cur[j], acc[i][j], 0, 0, 0);
        __builtin_amdgcn_s_setprio(0);
    };

    for (int kt = 0; kt + 2 <= KT; kt += 2) {
        body(kt,     bfA, bfB);
        body(kt + 1, bfB, bfA);
    }
    if (KT & 1) body(KT - 1, bfA, bfB);   // odd-KT tail (nc: KT=33)

    // epilogue: first barrier FULL drain (<=12 gld_lds writes may still be
    // in flight into As = tr); later barriers lgkm-only.
    _Float16* tr = As;
#pragma unroll
    for (int pass = 0; pass < 2; ++pass) {
        if (pass == 0) __syncthreads(); else bar_lgkm();
        if (wm == pass * 64) {
#pragma unroll
            for (int i = 0; i < 4; ++i) {
#pragma unroll
                for (int v = 0; v < 4; ++v) {
                    const int lr = i * 16 + l4 + v;
#pragma unroll
                    for (int j = 0; j < 4; ++j) {
                        const int cc = wn + j * 16 + l15;
                        float val = acc[i][j][v] + bias[c * 128 + cc];
                        val = fmaxf(val, 0.f);
                        tr[lr * 132 + cc] = (_Float16)val;
                    }
                }
            }
        }
        bar_lgkm();
#pragma unroll
        for (int it = 0; it < 4; ++it) {
            const int id = it * 256 + tid;
            const int r  = id & 63;
            const int cg = id >> 6;
            f16x4 lo = *(const f16x4*)(tr + r * 132 + cg * 8);
            f16x4 hi = *(const f16x4*)(tr + r * 132 + cg * 8 + 4);
            f16x8 v8;
#pragma unroll
            for (int t = 0; t < 4; ++t) { v8[t] = lo[t]; v8[t + 4] = hi[t]; }
            const int kti = ktOff + (c << 2) + (cg >> 2);
            const int gr  = pass * 64 + r;
            size_t o = (((size_t)p * KTo + kti) * 4 + (cg & 3)) * 1024 + (size_t)gr * 8;
            *(f16x8*)(C + o) = v8;
        }
    }
}

// ------------------------- blocked f16 MFMA GEMM (128-path) ----------------
template <int MODE>
__global__ __launch_bounds__(256, 4) void gemm_blk(
    const _Float16* __restrict__ A,      // blocked [MT][KTs]
    const _Float16* __restrict__ Wt,     // blocked [NT][KT] (dense)
    int KT, int KTs,
    const float* __restrict__ bias, int ldbias, const int* __restrict__ gbid,
    void* __restrict__ C, int KTo, int ktOff,   // mode 0: blocked f16 out
    int ldc,                                    // mode 1: f32 row-major out
    const int* __restrict__ srow, float* __restrict__ aux,  // m2: agg; m3: mw1
    int M, int relu)
{
    __shared__ char smem[32768];   // staging 2x16KB | m0 tr 16.9KB | m2 trf 16.6KB
    _Float16* As = (_Float16*)smem;          // 8192 f16
    _Float16* Bs = As + 8192;

    const int tid  = threadIdx.x;
    const int lane = tid & 63;
    const int wid  = tid >> 6;
    const int wm = (wid & 1) << 6;
    const int wn = (wid >> 1) << 6;

    // XCD swizzle: panel p's column-blocks share f%8 (same XCD)
    const int nb = gridDim.x;
    const int MT = gridDim.y;
    int f = blockIdx.y * nb + blockIdx.x;
    const int MT8 = MT & ~7;
    int p, c;
    if (f < MT8 * nb) {
        c = (f >> 3) % nb;
        p = (f & 7) + 8 * ((f >> 3) / nb);
    } else {
        int g = f - MT8 * nb;
        p = MT8 + g / nb;
        c = g % nb;
    }

    f32x4 acc[4][4];
#pragma unroll
    for (int i = 0; i < 4; ++i)
#pragma unroll
        for (int j = 0; j < 4; ++j) acc[i][j] = (f32x4){0.f, 0.f, 0.f, 0.f};

    const _Float16* pA = A + (size_t)p * KTs * 4096;
    const _Float16* pB = Wt + (size_t)c * KT * 4096;
    const int cb0 = wid * 64;
    const int cb1 = 256 + wid * 64;
    const int kq  = (lane >> 4) * 128;
    const int l15 = lane & 15;
    const int l4  = (lane >> 4) << 2;

    // main loop: BK=64 (two kt blocks per barrier pair)
    int kt = 0;
    for (; kt + 2 <= KT; kt += 2) {
        __syncthreads();
        gld_lds16(pA + (size_t)(cb0 + lane) * 8,        As + cb0 * 8);
        gld_lds16(pA + (size_t)(cb1 + lane) * 8,        As + cb1 * 8);
        gld_lds16(pA + 4096 + (size_t)(cb0 + lane) * 8, As + 4096 + cb0 * 8);
        gld_lds16(pA + 4096 + (size_t)(cb1 + lane) * 8, As + 4096 + cb1 * 8);
        gld_lds16(pB + (size_t)(cb0 + lane) * 8,        Bs + cb0 * 8);
        gld_lds16(pB + (size_t)(cb1 + lane) * 8,        Bs + cb1 * 8);
        gld_lds16(pB + 4096 + (size_t)(cb0 + lane) * 8, Bs + 4096 + cb0 * 8);
        gld_lds16(pB + 4096 + (size_t)(cb1 + lane) * 8, Bs + 4096 + cb1 * 8);
        pA += 8192; pB += 8192;
        __syncthreads();

#pragma unroll
        for (int s = 0; s < 2; ++s) {
            f16x8 af[4], bf[4];
            const int sb = s * 4096;
#pragma unroll
            for (int i = 0; i < 4; ++i)
                af[i] = *(const f16x8*)(As + sb + (size_t)((kq + wm + i * 16 + l15) << 3));
#pragma unroll
            for (int j = 0; j < 4; ++j)
                bf[j] = *(const f16x8*)(Bs + sb + (size_t)((kq + wn + j * 16 + l15) << 3));
#pragma unroll
            for (int i = 0; i < 4; ++i)
#pragma unroll
                for (int j = 0; j < 4; ++j)
                    acc[i][j] = __builtin_amdgcn_mfma_f32_16x16x32_f16(af[i], bf[j], acc[i][j], 0, 0, 0);
        }
    }
    // leftover: BK=32
    if (kt < KT) {
        __syncthreads();
        gld_lds16(pA + (size_t)(cb0 + lane) * 8, As + cb0 * 8);
        gld_lds16(pA + (size_t)(cb1 + lane) * 8, As + cb1 * 8);
        gld_lds16(pB + (size_t)(cb0 + lane) * 8, Bs + cb0 * 8);
        gld_lds16(pB + (size_t)(cb1 + lane) * 8, Bs + cb1 * 8);
        __syncthreads();
        f16x8 af[4], bf[4];
#pragma unroll
        for (int i = 0; i < 4; ++i)
            af[i] = *(const f16x8*)(As + (size_t)((kq + wm + i * 16 + l15) << 3));
#pragma unroll
        for (int j = 0; j < 4; ++j)
            bf[j] = *(const f16x8*)(Bs + (size_t)((kq + wn + j * 16 + l15) << 3));
#pragma unroll
        for (int i = 0; i < 4; ++i)
#pragma unroll
            for (int j = 0; j < 4; ++j)
                acc[i][j] = __builtin_amdgcn_mfma_f32_16x16x32_f16(af[i], bf[j], acc[i][j], 0, 0, 0);
    }
    // NOTE: all gld_lds writes drained by the last main-loop __syncthreads
    // before compute; no staging after -> epilogue barriers can be lgkm-only.

    if (MODE == 0) {
        // re-block C through LDS, two passes of 64 rows (tr = [64][132] f16)
        _Float16* tr = (_Float16*)smem;
#pragma unroll
        for (int pass = 0; pass < 2; ++pass) {
            bar_lgkm();
            if (wm == pass * 64) {
#pragma unroll
                for (int i = 0; i < 4; ++i) {
#pragma unroll
                    for (int v = 0; v < 4; ++v) {
                        const int lr = i * 16 + l4 + v;
                        const float* brow = bias;
                        if (gbid) {
                            int m = p * 128 + pass * 64 + lr;
                            if (m >= M) m = M - 1;
                            brow = bias + (size_t)clampi(gbid[m], BB) * ldbias;
                        }
#pragma unroll
                        for (int j = 0; j < 4; ++j) {
                            const int cc = wn + j * 16 + l15;
                            float val = acc[i][j][v] + brow[c * 128 + cc];
                            if (relu) val = fmaxf(val, 0.f);
                            tr[lr * 132 + cc] = (_Float16)val;
                        }
                    }
                }
            }
            bar_lgkm();
#pragma unroll
            for (int it = 0; it < 4; ++it) {
                const int id = it * 256 + tid;
                const int r  = id & 63;
                const int cg = id >> 6;
                f16x4 lo = *(const f16x4*)(tr + r * 132 + cg * 8);
                f16x4 hi = *(const f16x4*)(tr + r * 132 + cg * 8 + 4);
                f16x8 v8;
#pragma unroll
                for (int t = 0; t < 4; ++t) { v8[t] = lo[t]; v8[t + 4] = hi[t]; }
                const int kti = ktOff + (c << 2) + (cg >> 2);
                const int gr  = pass * 64 + r;
                size_t o = (((size_t)p * KTo + kti) * 4 + (cg & 3)) * 1024 + (size_t)gr * 8;
                *(f16x8*)((_Float16*)C + o) = v8;
            }
        }
    } else if (MODE == 1) {
#pragma unroll
        for (int i = 0; i < 4; ++i) {
#pragma unroll
            for (int v = 0; v < 4; ++v) {
                const int m = p * 128 + wm + i * 16 + l4 + v;
                if (m >= M) continue;
                const float* brow = bias;
                if (gbid) brow = bias + (size_t)clampi(gbid[m], BB) * ldbias;
#pragma unroll
                for (int j = 0; j < 4; ++j) {
                    const int col = c * 128 + wn + j * 16 + l15;
                    float val = acc[i][j][v] + brow[col];
                    if (relu) val = fmaxf(val, 0.f);
                    ((float*)C)[(size_t)m * ldc + col] = val;
                }
            }
        }
    } else if (MODE == 2) {
        // fused coalesced scatter-add. 4 passes of 32 rows. lgkm-only
        // barriers: atomics stream across passes (no vmcnt drains).
        float* trf = (float*)smem;   // [32][130] f32, 16640 B
#pragma unroll
        for (int pass = 0; pass < 4; ++pass) {
            bar_lgkm();
            if (wm == ((pass >> 1) << 6)) {
                const int i0 = (pass & 1) << 1;
#pragma unroll
                for (int ii = 0; ii < 2; ++ii) {
                    const int i = i0 + ii;
                    const int lr = ii * 16 + l4;
#pragma unroll
                    for (int v = 0; v < 4; ++v) {
#pragma unroll
                        for (int j = 0; j < 4; ++j) {
                            const int cc = wn + j * 16 + l15;
                            float val = acc[i][j][v] + bias[c * 128 + cc];
                            if (relu) val = fmaxf(val, 0.f);
                            trf[(lr + v) * 130 + cc] = val;
                        }
                    }
                }
            }
            bar_lgkm();
            const int ebase = p * 128 + pass * 32;
#pragma unroll
            for (int it = 0; it < 16; ++it) {
                const int id = it * 256 + tid;
                const int lr = id >> 7;
                const int colg = id & 127;
                const int el = ebase + lr;
                if (el < M) {
                    const int node = clampi(srow[el], NN);
                    atomicAdd(&aux[(size_t)node * 512 + c * 128 + colg],
                              trf[lr * 130 + colg]);
                }
            }
        }
    } else {
        // MODE 3: fused final dot. out[m] += sum_col relu(acc+bias[col])*mw1[col]
        const float* mw1 = aux;
        float* out = (float*)C;
#pragma unroll
        for (int i = 0; i < 4; ++i) {
#pragma unroll
            for (int v = 0; v < 4; ++v) {
                const int m = p * 128 + wm + i * 16 + l4 + v;
                const int mc = m < M ? m : M - 1;
                const float* brow = bias + (size_t)clampi(gbid[mc], BB) * ldbias;
                float s = 0.f;
#pragma unroll
                for (int j = 0; j < 4; ++j) {
                    const int col = c * 128 + wn + j * 16 + l15;
                    float val = acc[i][j][v] + brow[col];
                    val = fmaxf(val, 0.f);
                    s += val * mw1[col];
                }
                s += __shfl_down(s, 8, 16);
                s += __shfl_down(s, 4, 16);
                s += __shfl_down(s, 2, 16);
                s += __shfl_down(s, 1, 16);
                if (l15 == 0 && m < M) atomicAdd(&out[m], s);
            }
        }
    }
}

// ------------------------- helper kernels ----------------------------------

// fp32 -> blocked f16 [N/128][Kd/32].
// mode 0: plain; 1: e0 (k<19); 2: pack544; 4: transpose; 5: tail512
__global__ void k_w2h_blk(const float* __restrict__ src, _Float16* __restrict__ dst,
                          int N, int Ksrc, int Kd, int mode)
{
    int t = blockIdx.x * blockDim.x + threadIdx.x;
    if (t >= N * Kd) return;
    int n = t / Kd, k = t - n * Kd;
    float v = 0.f;
    if (mode == 0)      { if (k < Ksrc) v = src[(size_t)n * Ksrc + k]; }
    else if (mode == 1) { if (k < 19) v = src[(size_t)n * 275 + k]; }
    else if (mode == 2) { if (k < 9) v = src[(size_t)n * Ksrc + k];
                          else if (k >= 32 && k < 544) v = src[(size_t)n * Ksrc + 9 + (k - 32)]; }
    else if (mode == 4) { if (k < Ksrc) v = src[(size_t)k * N + n]; }
    else                { v = src[(size_t)n * Ksrc + 9 + k]; }
    int KT = Kd >> 5;
    int nt = n >> 7, r = n & 127, kt = k >> 5, kg = (k >> 3) & 3, ko = k & 7;
    dst[(((size_t)nt * KT + kt) * 4 + kg) * 1024 + (size_t)r * 8 + ko] = (_Float16)v;
}

// whnc kt32 slot: k' 0..31, value = nw0[n][k'] for k'<9 else 0
__global__ void k_fill_w32(const float* __restrict__ nw0, _Float16* __restrict__ whnc)
{
    int t = blockIdx.x * blockDim.x + threadIdx.x;
    if (t >= 512 * 32) return;
    int n = t >> 5, k = t & 31;
    float v = (k < 9) ? nw0[(size_t)n * 521 + k] : 0.f;
    int nt = n >> 7, r = n & 127, kg = (k >> 3) & 3, ko = k & 7;
    whnc[(((size_t)nt * 33 + 32) * 4 + kg) * 1024 + (size_t)r * 8 + ko] = (_Float16)v;
}

// bfused[n] = dot(nw0[n][9:521], eb4) + nb0[n]; one wave per n
__global__ void k_bfuse(const float* __restrict__ nw0, const float* __restrict__ eb4,
                        const float* __restrict__ nb0, float* __restrict__ bf)
{
    int wave = (blockIdx.x * 256 + threadIdx.x) >> 6;
    int lane = threadIdx.x & 63;
    if (wave >= 512) return;
    const float* wr = nw0 + (size_t)wave * 521 + 9;
    float s = 0.f;
#pragma unroll
    for (int i = 0; i < 8; ++i) s += wr[lane * 8 + i] * eb4[lane * 8 + i];
    for (int off = 32; off; off >>= 1) s += __shfl_down(s, off);
    if (lane == 0) bf[wave] = s + nb0[wave];
}

// u_r[16,256] fp32
__global__ void k_u_r(const float* __restrict__ u, const float* __restrict__ w_sel,
                      const float* __restrict__ b_sel, float* __restrict__ u_r)
{
    int wave = (blockIdx.x * 256 + threadIdx.x) >> 6;
    int lane = threadIdx.x & 63;
    int b = wave >> 8, n = wave & 255;
    const float4* u4 = (const float4*)(u + (size_t)b * 4096);
    const float4* w4 = (const float4*)(w_sel + (size_t)n * 4096);
    float s = 0.f;
    for (int i = lane; i < 1024; i += 64) {
        float4 a = u4[i], c = w4[i];
        s += a.x * c.x + a.y * c.y + a.z * c.z + a.w * c.w;
    }
    for (int off = 32; off; off >>= 1) s += __shfl_down(s, off);
    if (lane == 0) u_r[b * 256 + n] = s + b_sel[n];
}

// ub[16][Nout] = u_r @ w[:, koff:koff+256]^T + b
__global__ void k_graph_bias(const float* __restrict__ u_r, const float* __restrict__ w,
                             const float* __restrict__ b, float* __restrict__ ub,
                             int Nout, int Ksrc, int koff)
{
    int wave = (blockIdx.x * 256 + threadIdx.x) >> 6;
    int lane = threadIdx.x & 63;
    if (wave >= 16 * Nout) return;
    int g = wave / Nout, n = wave - g * Nout;
    const float* ur = u_r + (size_t)g * 256;
    const float* wr = w + (size_t)n * Ksrc + koff;
    float s = 0.f;
#pragma unroll
    for (int i = 0; i < 4; ++i) s += ur[lane * 4 + i] * wr[lane * 4 + i];
    for (int off = 32; off; off >>= 1) s += __shfl_down(s, off);
    if (lane == 0) ub[(size_t)g * Nout + n] = s + b[n];
}

// gbe + per-node edge count in one pass
__global__ void k_gbe(const int* __restrict__ row, const int* __restrict__ batch,
                      int* __restrict__ gbe, float* __restrict__ cnt)
{
    int e = blockIdx.x * blockDim.x + threadIdx.x;
    if (e >= EE) return;
    int r = clampi(row[e], NN);
    gbe[e] = clampi(batch[r], BB);
    atomicAdd(&cnt[r], 1.f);
}

// out[n] = mb1[0]  (atomic target init; d_out is poisoned pre-launch)
__global__ void k_init_out(float* __restrict__ out, const float* __restrict__ mb1)
{
    int t = blockIdx.x * blockDim.x + threadIdx.x;
    if (t < NN) out[t] = mb1[0];
}

// edge gather: e_in [MT][1] = [x[row](9)|x[col](9)|ea|0..]; ALSO writes
// x[col] into kt=32 slot of pong [MT][33] (used by nc GEMM).
__global__ void k_gather_edge_blk(const float* __restrict__ x, const float* __restrict__ ea,
                                  const int* __restrict__ row, const int* __restrict__ col,
                                  _Float16* __restrict__ dst, _Float16* __restrict__ pong,
                                  int e0, int ec, int MTR)
{
    int t = blockIdx.x * blockDim.x + threadIdx.x;
    if (t >= MTR * 4) return;
    int r = t >> 2, kg = t & 3;
    int e = e0 + r; int emax = e0 + ec - 1;
    if (e > emax) e = emax;
    int ri = clampi(row[e], NN), ci = clampi(col[e], NN);
    f16x8 v;
    f16x8 vx = (f16x8)(_Float16)0.f;
#pragma unroll
    for (int j = 0; j < 8; ++j) {
        int cc = kg * 8 + j;
        float fv = 0.f;
        if (cc < 9)       fv = x[(size_t)ri * 9 + cc];
        else if (cc < 18) fv = x[(size_t)ci * 9 + (cc - 9)];
        else if (cc == 18) fv = ea[e];
        v[j] = (_Float16)fv;
        if (cc < 9) vx[j] = (_Float16)x[(size_t)ci * 9 + cc];
    }
    *(f16x8*)(dst + (size_t)(r >> 7) * 4096 + (size_t)kg * 1024 + (size_t)(r & 127) * 8) = v;
    *(f16x8*)(pong + (((size_t)(r >> 7) * 33 + 32) * 4 + kg) * 1024 + (size_t)(r & 127) * 8) = vx;
}

// m_in blocked [MTm][17]: cols = [x(9)|pad23 | agg/cnt(512)]
__global__ void k_gather_min(const float* __restrict__ x, const float* __restrict__ agg,
                             const float* __restrict__ cnt, _Float16* __restrict__ dst, int MTR)
{
    int t = blockIdx.x * blockDim.x + threadIdx.x;
    if (t >= MTR * 68) return;
    int r = t / 68, q = t - r * 68;
    int kt = q >> 2, kg = q & 3;
    int n = r < NN ? r : NN - 1;
    f16x8 v = (f16x8)(_Float16)0.f;
    if (kt == 0) {
#pragma unroll
        for (int j = 0; j < 8; ++j) {
            int cc = kg * 8 + j;
            if (cc < 9) v[j] = (_Float16)x[(size_t)n * 9 + cc];
        }
    } else {
        float inv = 1.f / fmaxf(cnt[n], 1.f);
        int cbase = (kt - 1) * 32 + kg * 8;
        const float4* ap = (const float4*)(agg + (size_t)n * 512 + cbase);
        float4 a0 = ap[0], a1 = ap[1];
        v[0] = (_Float16)(a0.x * inv); v[1] = (_Float16)(a0.y * inv);
        v[2] = (_Float16)(a0.z * inv); v[3] = (_Float16)(a0.w * inv);
        v[4] = (_Float16)(a1.x * inv); v[5] = (_Float16)(a1.y * inv);
        v[6] = (_Float16)(a1.z * inv); v[7] = (_Float16)(a1.w * inv);
    }
    *(f16x8*)(dst + ((size_t)(r >> 7) * 17 + kt) * 4096 + (size_t)kg * 1024 + (size_t)(r & 127) * 8) = v;
}

// ------------------------------- host --------------------------------------

#define GRID1(n) dim3(((n) + 255) / 256)

static inline void gemmB0(hipStream_t s, const _Float16* A, const _Float16* Wt, int KT, int KTs,
                          const float* bias, int ldbias, const int* gbid,
                          void* C, int KTo, int ktOff,
                          int M, int MT, int NT, int relu)
{
    hipLaunchKernelGGL(gemm_blk<0>, dim3(NT, MT), dim3(256), 0, s,
                       A, Wt, KT, KTs, bias, ldbias, gbid, C, KTo, ktOff, 0,
                       nullptr, nullptr, M, relu);
}
static inline void gemmB2(hipStream_t s, const _Float16* A, const _Float16* Wt, int KT, int KTs,
                          const float* bias, const int* srow, float* agg,
                          int M, int MT, int NT, int relu)
{
    hipLaunchKernelGGL(gemm_blk<2>, dim3(NT, MT), dim3(256), 0, s,
                       A, Wt, KT, KTs, bias, 0, nullptr, nullptr, 0, 0, 0,
                       srow, agg, M, relu);
}
static inline void gemmB3(hipStream_t s, const _Float16* A, const _Float16* Wt, int KT, int KTs,
                          const float* bias, int ldbias, const int* gbid,
                          float* out, const float* mw1,
                          int M, int MT, int NT)
{
    hipLaunchKernelGGL(gemm_blk<3>, dim3(NT, MT), dim3(256), 0, s,
                       A, Wt, KT, KTs, bias, ldbias, gbid, out, 0, 0, 0,
                       nullptr, (float*)mw1, M, 1);
}

extern "C" void kernel_launch(void* const* d_in, const int* in_sizes, int n_in,
                              void* d_out, int out_size, void* d_ws, size_t ws_size,
                              hipStream_t stream)
{
    const float* x     = (const float*)d_in[0];
    const int*   ei    = (const int*)d_in[1];
    const float* ea    = (const float*)d_in[2];
    const float* u     = (const float*)d_in[3];
    const int*   batch = (const int*)d_in[4];
    const float* w_sel = (const float*)d_in[5];
    const float* b_sel = (const float*)d_in[6];
    const float* ew0 = (const float*)d_in[7];   const float* eb0 = (const float*)d_in[8];
    const float* ew1 = (const float*)d_in[9];   const float* eb1 = (const float*)d_in[10];
    const float* ew2 = (const float*)d_in[11];  const float* eb2 = (const float*)d_in[12];
    const float* ew3 = (const float*)d_in[13];  const float* eb3 = (const float*)d_in[14];
    const float* ew4 = (const float*)d_in[15];  const float* eb4 = (const float*)d_in[16];
    const float* nw0 = (const float*)d_in[17];  const float* nb0 = (const float*)d_in[18];
    const float* nw1 = (const float*)d_in[19];  const float* nb1 = (const float*)d_in[20];
    const float* mw0 = (const float*)d_in[21];  const float* mb0 = (const float*)d_in[22];
    const float* mw1 = (const float*)d_in[23];  const float* mb1 = (const float*)d_in[24];

    const int* row = ei;
    const int* col = ei + EE;

    char* W = (char*)d_ws;
    size_t off = 0;
    auto alloc = [&](size_t bytes) -> char* {
        char* p = W + off;
        off = (off + bytes + 255) & ~(size_t)255;
        return p;
    };
    float*    cnt   = (float*)alloc(20000 * 4);
    float*    agg   = (float*)alloc((size_t)NN * 512 * 4);
    float*    zbias = (float*)alloc(1024 * 4);          // stays zero (for W_comb GEMM)
    const size_t zeroBytes = off;
    float*    u_r  = (float*)alloc(16 * 256 * 4);
    float*    ub0  = (float*)alloc(16 * 1024 * 4);
    float*    ubm  = (float*)alloc(16 * 512 * 4);
    float*    bfu  = (float*)alloc(512 * 4);            // fused nc bias
    int*      gbe  = (int*)alloc((size_t)EE * 4);
    _Float16* wh0   = (_Float16*)alloc((size_t)8 * 1 * 4096 * 2);
    _Float16* wh1   = (_Float16*)alloc((size_t)8 * 32 * 4096 * 2);
    _Float16* wh2   = (_Float16*)alloc((size_t)8 * 32 * 4096 * 2);
    _Float16* wh3   = (_Float16*)alloc((size_t)8 * 32 * 4096 * 2);
    _Float16* whnc  = (_Float16*)alloc((size_t)4 * 33 * 4096 * 2);  // [W_comb | nw0_x]
    _Float16* whn1  = (_Float16*)alloc((size_t)4 * 16 * 4096 * 2);
    _Float16* whm0  = (_Float16*)alloc((size_t)4 * 17 * 4096 * 2);
    _Float16* nw0eoB= (_Float16*)alloc((size_t)4 * 16 * 4096 * 2);  // nw0[:,9:521] blocked
    _Float16* ew4T  = (_Float16*)alloc((size_t)8 * 16 * 4096 * 2);  // ew4^T blocked
    const int MTm = (NN + 127) / 128;           // 157
    _Float16* m_in = (_Float16*)alloc((size_t)MTm * 17 * 4096 * 2);
    const size_t fixedBytes = off;

    // choose edge chunk (depends only on ws_size -> capture-safe).
    // 32768 -> gemm256h grid 8x128 = 1024 blocks = 2.00 rounds @2 blk/CU.
    static const int ecOpts[] = {32768, 25000, 12500, 10000, 5000};
    int EC = 5000;
    for (int i = 0; i < 5; ++i) {
        int ec = ecOpts[i];
        size_t MTRc = (size_t)((ec + 255) / 256) * 256;
        size_t need = fixedBytes + MTRc * 64 + 2 * (MTRc * 2112) + 4096;
        if (need <= ws_size) { EC = ec; break; }
    }
    const bool big = (EC == 32768);
    const size_t MTR = (size_t)((EC + 255) / 256) * 256;
    _Float16* e_in = (_Float16*)alloc(MTR * 64);        // [MT][1]
    _Float16* ping = (_Float16*)alloc(MTR * 2112);      // [MT][33]
    _Float16* pong = (_Float16*)alloc(MTR * 2112);      // [MT][33]
    const int NCH = (EE + EC - 1) / EC;

    (void)hipMemsetAsync(W, 0, zeroBytes, stream);
    hipLaunchKernelGGL(k_init_out, GRID1(NN), dim3(256), 0, stream, (float*)d_out, mb1);

    hipLaunchKernelGGL(k_u_r, dim3(1024), dim3(256), 0, stream, u, w_sel, b_sel, u_r);
    hipLaunchKernelGGL(k_graph_bias, GRID1(16 * 1024 * 64), dim3(256), 0, stream,
                       u_r, ew0, eb0, ub0, 1024, 275, 19);
    hipLaunchKernelGGL(k_graph_bias, GRID1(16 * 512 * 64), dim3(256), 0, stream,
                       u_r, mw0, mb0, ubm, 512, 777, 521);
    hipLaunchKernelGGL(k_gbe, GRID1(EE), dim3(256), 0, stream, row, batch, gbe, cnt);
    hipLaunchKernelGGL(k_bfuse, dim3(128), dim3(256), 0, stream, nw0, eb4, nb0, bfu);

    auto pack = [&](const float* w, _Float16* wh, int N, int Ksrc, int Kd, int mode) {
        hipLaunchKernelGGL(k_w2h_blk, GRID1(N * Kd), dim3(256), 0, stream, w, wh, N, Ksrc, Kd, mode);
    };
    pack(ew0, wh0, 1024, 275, 32, 1);
    pack(ew1, wh1, 1024, 1024, 1024, 0);
    pack(ew2, wh2, 1024, 1024, 1024, 0);
    pack(ew3, wh3, 1024, 1024, 1024, 0);
    pack(nw1, whn1, 512, 512, 512, 0);
    pack(mw0, whm0, 512, 777, 544, 2);
    pack(nw0, nw0eoB, 512, 521, 512, 5);    // nw0[:,9:521]
    pack(ew4, ew4T, 1024, 512, 512, 4);     // ew4^T  (v = ew4[k][n])
    // W_comb = nw0eo @ ew4 : M=512, N=1024, K=512 -> whnc kt 0..31 (blocked out)
    gemmB0(stream, nw0eoB, ew4T, 16, 16, zbias, 0, nullptr, whnc, 33, 0, 512, 4, 8, 0);
    hipLaunchKernelGGL(k_fill_w32, GRID1(512 * 32), dim3(256), 0, stream, nw0, whnc);

    for (int ch = 0; ch < NCH; ++ch) {
        int e0 = ch * EC;
        int ec = EC; if (e0 + ec > EE) ec = EE - e0;
        const int ecr  = ((ec + 255) / 256) * 256;   // rows processed this chunk
        const int MTc  = ecr / 128;
        const int MT2c = ecr / 256;
        // edge gather (also fills pong kt=32 with x[col] for the nc GEMM)
        hipLaunchKernelGGL(k_gather_edge_blk, GRID1(ecr * 4), dim3(256), 0, stream,
                           x, ea, row, col, e_in, pong, e0, ec, ecr);
        // l0: K=32, per-graph bias ub0 (128-path)
        gemmB0(stream, e_in, wh0, 1, 1, ub0, 1024, gbe + e0, ping, 33, 0, ec, MTc, 8, 1);
        // l1..l3: big -> 4-wave 256x128 2-blk/CU path; else A-ring/B-direct
        auto wideL = [&](const _Float16* Ain, const _Float16* Wt,
                         const float* b, _Float16* Cout) {
            if (big)
                hipLaunchKernelGGL(gemm256h, dim3(8, MT2c), dim3(256), 0, stream,
                                   Ain, Wt, 32, 33, b, Cout, 33, 0);
            else
                hipLaunchKernelGGL(gemmAD, dim3(8, MTc), dim3(256), 0, stream,
                                   Ain, Wt, 32, 33, b, Cout, 33, 0);
        };
        wideL(ping, wh1, eb1, pong);
        wideL(pong, wh2, eb2, ping);
        wideL(ping, wh3, eb3, pong);
        // nc: fused (ew4+nw0) GEMM, K=1056, KT=33 (odd tail in gemmAD)
        hipLaunchKernelGGL(gemmAD, dim3(4, MTc), dim3(256), 0, stream,
                           pong, whnc, 33, 33, bfu, ping, 16, 0);
        // n1: fused COALESCED scatter-add into agg (mode 2)
        gemmB2(stream, ping, whn1, 16, 16, nb1, row + e0, agg, ec, MTc, 4, 1);
    }

    hipLaunchKernelGGL(k_gather_min, GRID1((int)(MTm * 128) * 68), dim3(256), 0, stream,
                       x, agg, cnt, m_in, MTm * 128);
    // m0 + final fused (mode 3): out[m] = mb1 + relu(m_in@mw0^T + ubm[batch]).mw1
    gemmB3(stream, m_in, whm0, 17, 17, ubm, 512, batch, (float*)d_out, mw1, NN, MTm, 4);
}

// Round 10
// 1394.976 us; speedup vs baseline: 1.0195x; 1.0195x over previous
//
#include <hip/hip_runtime.h>

// ---------------------------------------------------------------------------
// OGRENet GraphNet block — f16 MFMA, BLOCKED operands.
// Blocked layout (f16): offset(m,k) = ((mt*KTo + kt)*4 + kg)*1024 + r*8 + ko
// R12: ew4+nw0 folded; R13: k_final folded into m0 (MODE=3).
// R18: EC=32768 full-fill. R19: read-12-frags + 1 barrier/phase.
// R20: WAR-prefetch into MFMA source regs REGRESSED (hazard). Reverted.
// R21: gemm256h 4-wave 256x128, 2 blk/CU — WIN 1381us. Top cost -> n1
//      atomic scatter (73us x4).
// R22: lgkm-only barriers: n1 UNCHANGED (73.1us) -> atomic-drain theory
//      falsified; n1 is raw atomic-RMW-throughput-bound (agg 41MB > L2,
//      0.92 TB/s atomic traffic, nothing else saturated).
// R23: ELIMINATE the atomics — CSR gather:
//      (1) n1 GEMM -> MODE 4: row-major f16 h_all (same verified LDS
//          transpose as MODE 0, 256B coalesced segments);
//      (2) CSR from cnt: k_scan (1 block, 1024 thr, Hillis-Steele) ->
//          ptr/cur; k_csr_fill places edge ids (100K cheap atomics);
//      (3) k_gather_csr: block/node, thread/2-cols, coalesced 1KB row
//          reads, mean, writes m_in blocked DIRECTLY (k_gather_min and
//          agg + its memset removed).
//      Host picks CSR path only if ws fits (+103MB h_all, -41MB agg);
//      fallback = R21/R22 path unchanged. Pad rows never referenced.
// [R8: template MODE; R7: rocprof replay overstates atomic kernels ~20x.]
// ---------------------------------------------------------------------------

#define NN 20000
#define EE 100000
#define BB 16

typedef _Float16 f16x8 __attribute__((ext_vector_type(8)));
typedef _Float16 f16x4 __attribute__((ext_vector_type(4)));
typedef _Float16 f16x2 __attribute__((ext_vector_type(2)));
typedef float f32x4 __attribute__((ext_vector_type(4)));

__device__ __forceinline__ int clampi(int v, int hi) {
    return v < 0 ? 0 : (v >= hi ? hi - 1 : v);
}

__device__ __forceinline__ void gld_lds16(const void* g, void* l) {
    __builtin_amdgcn_global_load_lds(
        (const __attribute__((address_space(1))) unsigned int*)g,
        (__attribute__((address_space(3))) unsigned int*)l, 16, 0, 0);
}

// barrier that orders LDS (lgkm) but lets VMEM stores/atomics stay in flight
__device__ __forceinline__ void bar_lgkm() {
    asm volatile("s_waitcnt lgkmcnt(0)" ::: "memory");
    __builtin_amdgcn_s_barrier();
}

// -------- 256x128-tile 4-wave GEMM, 2 regions, 2 blocks/CU (R21) -----------
__global__ __launch_bounds__(256, 2) void gemm256h(
    const _Float16* __restrict__ Ag, const _Float16* __restrict__ Wt,
    int KT, int KTs, const float* __restrict__ bias,
    _Float16* __restrict__ C, int KTo, int ktOff)
{
    __shared__ _Float16 smem[24576];   // 2 regions x (A 8192 + B 4096) f16

    const int tid  = threadIdx.x;
    const int lane = tid & 63;
    const int wid  = tid >> 6;       // 0..3
    const int wm   = wid & 1;        // row page (128 rows)
    const int wn   = wid >> 1;       // col half (64 cols)
    const int l15  = lane & 15;
    const int l4   = (lane >> 4) << 2;
    const int kq   = (lane >> 4) << 10;

    const int nb  = gridDim.x;       // 8
    const int MT2 = gridDim.y;
    int f = blockIdx.y * nb + blockIdx.x;
    const int MT8 = MT2 & ~7;
    int p, c;
    if (f < MT8 * nb) {
        c = (f >> 3) % nb;
        p = (f & 7) + 8 * ((f >> 3) / nb);
    } else {
        int g = f - MT8 * nb;
        p = MT8 + g / nb;
        c = g % nb;
    }

    const int S = KT;                // phases; gemm256h only sees even S
    auto stage = [&](int ph) {
        const _Float16* gA0 = Ag + ((size_t)(2 * p)     * KTs + ph) * 4096 + tid * 8;
        const _Float16* gA1 = Ag + ((size_t)(2 * p + 1) * KTs + ph) * 4096 + tid * 8;
        const _Float16* gB  = Wt + ((size_t)c * KT + ph) * 4096 + tid * 8;
        _Float16* rA = smem + (ph & 1) * 12288;
        _Float16* rB = rA + 8192;
        gld_lds16(gA0,        rA + wid * 512);
        gld_lds16(gA0 + 2048, rA + 2048 + wid * 512);
        gld_lds16(gA1,        rA + 4096 + wid * 512);
        gld_lds16(gA1 + 2048, rA + 6144 + wid * 512);
        gld_lds16(gB,         rB + wid * 512);
        gld_lds16(gB + 2048,  rB + 2048 + wid * 512);
    };

    f32x4 acc[8][4];
#pragma unroll
    for (int i = 0; i < 8; ++i)
#pragma unroll
        for (int j = 0; j < 4; ++j) acc[i][j] = (f32x4){0.f, 0.f, 0.f, 0.f};

    stage(0);

    for (int s = 0; s < S; ++s) {
        asm volatile("s_waitcnt vmcnt(0)" ::: "memory");
        __builtin_amdgcn_s_barrier();
        if (s + 1 < S) stage(s + 1);
        const _Float16* rA = smem + (s & 1) * 12288;
        const _Float16* rB = rA + 8192;
        const _Float16* Ap = rA + wm * 4096 + kq + l15 * 8;
        const _Float16* Bp = rB + kq + wn * 512 + l15 * 8;
        f16x8 af[8], bf[4];
#pragma unroll
        for (int j = 0; j < 4; ++j) bf[j] = *(const f16x8*)(Bp + j * 128);
#pragma unroll
        for (int i = 0; i < 8; ++i) af[i] = *(const f16x8*)(Ap + i * 128);
        __builtin_amdgcn_s_setprio(1);
#pragma unroll
        for (int i = 0; i < 8; ++i)
#pragma unroll
            for (int j = 0; j < 4; ++j)
                acc[i][j] = __builtin_amdgcn_mfma_f32_16x16x32_f16(
                    af[i], bf[j], acc[i][j], 0, 0, 0);
        __builtin_amdgcn_s_setprio(0);
    }

    // epilogue: 4 passes of 64 rows; tr = [64][132] f16
    _Float16* tr = smem;
#pragma unroll
    for (int pass = 0; pass < 4; ++pass) {
        bar_lgkm();
        if (wm == (pass >> 1)) {
            const int fi = (pass & 1) << 2;
#pragma unroll
            for (int i = 0; i < 4; ++i) {
#pragma unroll
                for (int v = 0; v < 4; ++v) {
                    const int lr = i * 16 + l4 + v;
#pragma unroll
                    for (int j = 0; j < 4; ++j) {
                        const int cc = wn * 64 + j * 16 + l15;
                        float val = acc[fi + i][j][v] + bias[c * 128 + cc];
                        val = fmaxf(val, 0.f);
                        tr[lr * 132 + cc] = (_Float16)val;
                    }
                }
            }
        }
        bar_lgkm();
#pragma unroll
        for (int it = 0; it < 4; ++it) {
            const int id = it * 256 + tid;
            const int r  = id & 63;
            const int cg = id >> 6;        // 0..15 (128 cols)
            f16x4 lo = *(const f16x4*)(tr + r * 132 + cg * 8);
            f16x4 hi = *(const f16x4*)(tr + r * 132 + cg * 8 + 4);
            f16x8 v8;
#pragma unroll
            for (int t = 0; t < 4; ++t) { v8[t] = lo[t]; v8[t + 4] = hi[t]; }
            const int kti = ktOff + (c << 2) + (cg >> 2);
            const int mt_out = 2 * p + (pass >> 1);
            const int r128 = ((pass & 1) << 6) + r;
            *(f16x8*)(C + (((size_t)mt_out * KTo + kti) * 4 + (cg & 3)) * 1024
                        + (size_t)r128 * 8) = v8;
        }
    }
}

// ------------- 128x128 A-in-LDS-ring / B-direct GEMM (R16, verified) -------
__global__ __launch_bounds__(256, 3) void gemmAD(
    const _Float16* __restrict__ Ag, const _Float16* __restrict__ Wt,
    int KT, int KTs, const float* __restrict__ bias,
    _Float16* __restrict__ C, int KTo, int ktOff)
{
    __shared__ _Float16 As[16384];   // 4-slot ring x 4096 f16 = 32 KB

    const int tid  = threadIdx.x;
    const int lane = tid & 63;
    const int wid  = tid >> 6;
    const int wm = (wid & 1) << 6;
    const int wn = (wid >> 1) << 6;
    const int l15 = lane & 15;
    const int l4  = (lane >> 4) << 2;
    const int kg  = (lane >> 4) << 10;

    const int nb = gridDim.x;
    const int MT = gridDim.y;
    int f = blockIdx.y * nb + blockIdx.x;
    const int MT8 = MT & ~7;
    int p, c;
    if (f < MT8 * nb) {
        c = (f >> 3) % nb;
        p = (f & 7) + 8 * ((f >> 3) / nb);
    } else {
        int g = f - MT8 * nb;
        p = MT8 + g / nb;
        c = g % nb;
    }

    f32x4 acc[4][4];
#pragma unroll
    for (int i = 0; i < 4; ++i)
#pragma unroll
        for (int j = 0; j < 4; ++j) acc[i][j] = (f32x4){0.f, 0.f, 0.f, 0.f};

    const _Float16* gA = Ag + (size_t)p * KTs * 4096;
    const _Float16* gB = Wt + ((size_t)c * KT) * 4096 + kg + (wn + l15) * 8;
    const int ktLim = KT - 1;

    auto stageA = [&](int ktA) {
        const _Float16* s = gA + (size_t)ktA * 4096 + tid * 8;
        _Float16* d = As + ((ktA & 3) << 12) + wid * 512;
        gld_lds16(s, d);
        gld_lds16(s + 2048, d + 2048);
    };

    f16x8 bfA[4], bfB[4];
    auto loadB = [&](f16x8 (&bf)[4], int ktB) {
        const _Float16* bp = gB + (size_t)ktB * 4096;
#pragma unroll
        for (int j = 0; j < 4; ++j) bf[j] = *(const f16x8*)(bp + j * 128);
    };

    stageA(0);
    stageA(1 <= ktLim ? 1 : ktLim);
    loadB(bfA, 0);

    auto body = [&](int kt, f16x8 (&cur)[4], f16x8 (&nxt)[4]) {
        const int ktB = kt + 1 <= ktLim ? kt + 1 : ktLim;
        const int ktA = kt + 2 <= ktLim ? kt + 2 : ktLim;
        loadB(nxt, ktB);
        stageA(ktA);
        asm volatile("s_waitcnt vmcnt(12)" ::: "memory");
        __builtin_amdgcn_s_barrier();
        asm volatile("" ::: "memory");
        const _Float16* Ap = As + ((kt & 3) << 12) + kg + (wm + l15) * 8;
        f16x8 af[4];
#pragma unroll
        for (int i = 0; i < 4; ++i) af[i] = *(const f16x8*)(Ap + i * 128);
        __builtin_amdgcn_s_setprio(1);
#pragma unroll
        for (int i = 0; i < 4; ++i)
#pragma unroll
            for (int j = 0; j < 4; ++j)
                acc[i][j] = __builtin_amdgcn_mfma_f32_16x16x32_f16(
                    af[i], cur[j], acc[i][j], 0, 0, 0);
        __builtin_amdgcn_s_setprio(0);
    };

    for (int kt = 0; kt + 2 <= KT; kt += 2) {
        body(kt,     bfA, bfB);
        body(kt + 1, bfB, bfA);
    }
    if (KT & 1) body(KT - 1, bfA, bfB);   // odd-KT tail (nc: KT=33)

    // epilogue: first barrier FULL drain (<=12 gld_lds writes outstanding
    // into As = tr); later barriers lgkm-only.
    _Float16* tr = As;
#pragma unroll
    for (int pass = 0; pass < 2; ++pass) {
        if (pass == 0) __syncthreads(); else bar_lgkm();
        if (wm == pass * 64) {
#pragma unroll
            for (int i = 0; i < 4; ++i) {
#pragma unroll
                for (int v = 0; v < 4; ++v) {
                    const int lr = i * 16 + l4 + v;
#pragma unroll
                    for (int j = 0; j < 4; ++j) {
                        const int cc = wn + j * 16 + l15;
                        float val = acc[i][j][v] + bias[c * 128 + cc];
                        val = fmaxf(val, 0.f);
                        tr[lr * 132 + cc] = (_Float16)val;
                    }
                }
            }
        }
        bar_lgkm();
#pragma unroll
        for (int it = 0; it < 4; ++it) {
            const int id = it * 256 + tid;
            const int r  = id & 63;
            const int cg = id >> 6;
            f16x4 lo = *(const f16x4*)(tr + r * 132 + cg * 8);
            f16x4 hi = *(const f16x4*)(tr + r * 132 + cg * 8 + 4);
            f16x8 v8;
#pragma unroll
            for (int t = 0; t < 4; ++t) { v8[t] = lo[t]; v8[t + 4] = hi[t]; }
            const int kti = ktOff + (c << 2) + (cg >> 2);
            const int gr  = pass * 64 + r;
            size_t o = (((size_t)p * KTo + kti) * 4 + (cg & 3)) * 1024 + (size_t)gr * 8;
            *(f16x8*)(C + o) = v8;
        }
    }
}

// ------------------------- blocked f16 MFMA GEMM (128-path) ----------------
// MODE 0: blocked f16 out; 1: f32 row-major; 2: atomic scatter-add (fallback
// path); 3: fused final dot; 4: ROW-MAJOR f16 out (h_all for CSR gather).
template <int MODE>
__global__ __launch_bounds__(256, 4) void gemm_blk(
    const _Float16* __restrict__ A,      // blocked [MT][KTs]
    const _Float16* __restrict__ Wt,     // blocked [NT][KT] (dense)
    int KT, int KTs,
    const float* __restrict__ bias, int ldbias, const int* __restrict__ gbid,
    void* __restrict__ C, int KTo, int ktOff,
    int ldc,
    const int* __restrict__ srow, float* __restrict__ aux,
    int M, int relu)
{
    __shared__ char smem[32768];
    _Float16* As = (_Float16*)smem;          // 8192 f16
    _Float16* Bs = As + 8192;

    const int tid  = threadIdx.x;
    const int lane = tid & 63;
    const int wid  = tid >> 6;
    const int wm = (wid & 1) << 6;
    const int wn = (wid >> 1) << 6;

    const int nb = gridDim.x;
    const int MT = gridDim.y;
    int f = blockIdx.y * nb + blockIdx.x;
    const int MT8 = MT & ~7;
    int p, c;
    if (f < MT8 * nb) {
        c = (f >> 3) % nb;
        p = (f & 7) + 8 * ((f >> 3) / nb);
    } else {
        int g = f - MT8 * nb;
        p = MT8 + g / nb;
        c = g % nb;
    }

    f32x4 acc[4][4];
#pragma unroll
    for (int i = 0; i < 4; ++i)
#pragma unroll
        for (int j = 0; j < 4; ++j) acc[i][j] = (f32x4){0.f, 0.f, 0.f, 0.f};

    const _Float16* pA = A + (size_t)p * KTs * 4096;
    const _Float16* pB = Wt + (size_t)c * KT * 4096;
    const int cb0 = wid * 64;
    const int cb1 = 256 + wid * 64;
    const int kq  = (lane >> 4) * 128;
    const int l15 = lane & 15;
    const int l4  = (lane >> 4) << 2;

    int kt = 0;
    for (; kt + 2 <= KT; kt += 2) {
        __syncthreads();
        gld_lds16(pA + (size_t)(cb0 + lane) * 8,        As + cb0 * 8);
        gld_lds16(pA + (size_t)(cb1 + lane) * 8,        As + cb1 * 8);
        gld_lds16(pA + 4096 + (size_t)(cb0 + lane) * 8, As + 4096 + cb0 * 8);
        gld_lds16(pA + 4096 + (size_t)(cb1 + lane) * 8, As + 4096 + cb1 * 8);
        gld_lds16(pB + (size_t)(cb0 + lane) * 8,        Bs + cb0 * 8);
        gld_lds16(pB + (size_t)(cb1 + lane) * 8,        Bs + cb1 * 8);
        gld_lds16(pB + 4096 + (size_t)(cb0 + lane) * 8, Bs + 4096 + cb0 * 8);
        gld_lds16(pB + 4096 + (size_t)(cb1 + lane) * 8, Bs + 4096 + cb1 * 8);
        pA += 8192; pB += 8192;
        __syncthreads();

#pragma unroll
        for (int s = 0; s < 2; ++s) {
            f16x8 af[4], bf[4];
            const int sb = s * 4096;
#pragma unroll
            for (int i = 0; i < 4; ++i)
                af[i] = *(const f16x8*)(As + sb + (size_t)((kq + wm + i * 16 + l15) << 3));
#pragma unroll
            for (int j = 0; j < 4; ++j)
                bf[j] = *(const f16x8*)(Bs + sb + (size_t)((kq + wn + j * 16 + l15) << 3));
#pragma unroll
            for (int i = 0; i < 4; ++i)
#pragma unroll
                for (int j = 0; j < 4; ++j)
                    acc[i][j] = __builtin_amdgcn_mfma_f32_16x16x32_f16(af[i], bf[j], acc[i][j], 0, 0, 0);
        }
    }
    if (kt < KT) {
        __syncthreads();
        gld_lds16(pA + (size_t)(cb0 + lane) * 8, As + cb0 * 8);
        gld_lds16(pA + (size_t)(cb1 + lane) * 8, As + cb1 * 8);
        gld_lds16(pB + (size_t)(cb0 + lane) * 8, Bs + cb0 * 8);
        gld_lds16(pB + (size_t)(cb1 + lane) * 8, Bs + cb1 * 8);
        __syncthreads();
        f16x8 af[4], bf[4];
#pragma unroll
        for (int i = 0; i < 4; ++i)
            af[i] = *(const f16x8*)(As + (size_t)((kq + wm + i * 16 + l15) << 3));
#pragma unroll
        for (int j = 0; j < 4; ++j)
            bf[j] = *(const f16x8*)(Bs + (size_t)((kq + wn + j * 16 + l15) << 3));
#pragma unroll
        for (int i = 0; i < 4; ++i)
#pragma unroll
            for (int j = 0; j < 4; ++j)
                acc[i][j] = __builtin_amdgcn_mfma_f32_16x16x32_f16(af[i], bf[j], acc[i][j], 0, 0, 0);
    }
    // all gld_lds drained by last main-loop __syncthreads before compute.

    if (MODE == 0) {
        _Float16* tr = (_Float16*)smem;
#pragma unroll
        for (int pass = 0; pass < 2; ++pass) {
            bar_lgkm();
            if (wm == pass * 64) {
#pragma unroll
                for (int i = 0; i < 4; ++i) {
#pragma unroll
                    for (int v = 0; v < 4; ++v) {
                        const int lr = i * 16 + l4 + v;
                        const float* brow = bias;
                        if (gbid) {
                            int m = p * 128 + pass * 64 + lr;
                            if (m >= M) m = M - 1;
                            brow = bias + (size_t)clampi(gbid[m], BB) * ldbias;
                        }
#pragma unroll
                        for (int j = 0; j < 4; ++j) {
                            const int cc = wn + j * 16 + l15;
                            float val = acc[i][j][v] + brow[c * 128 + cc];
                            if (relu) val = fmaxf(val, 0.f);
                            tr[lr * 132 + cc] = (_Float16)val;
                        }
                    }
                }
            }
            bar_lgkm();
#pragma unroll
            for (int it = 0; it < 4; ++it) {
                const int id = it * 256 + tid;
                const int r  = id & 63;
                const int cg = id >> 6;
                f16x4 lo = *(const f16x4*)(tr + r * 132 + cg * 8);
                f16x4 hi = *(const f16x4*)(tr + r * 132 + cg * 8 + 4);
                f16x8 v8;
#pragma unroll
                for (int t = 0; t < 4; ++t) { v8[t] = lo[t]; v8[t + 4] = hi[t]; }
                const int kti = ktOff + (c << 2) + (cg >> 2);
                const int gr  = pass * 64 + r;
                size_t o = (((size_t)p * KTo + kti) * 4 + (cg & 3)) * 1024 + (size_t)gr * 8;
                *(f16x8*)((_Float16*)C + o) = v8;
            }
        }
    } else if (MODE == 1) {
#pragma unroll
        for (int i = 0; i < 4; ++i) {
#pragma unroll
            for (int v = 0; v < 4; ++v) {
                const int m = p * 128 + wm + i * 16 + l4 + v;
                if (m >= M) continue;
                const float* brow = bias;
                if (gbid) brow = bias + (size_t)clampi(gbid[m], BB) * ldbias;
#pragma unroll
                for (int j = 0; j < 4; ++j) {
                    const int col = c * 128 + wn + j * 16 + l15;
                    float val = acc[i][j][v] + brow[col];
                    if (relu) val = fmaxf(val, 0.f);
                    ((float*)C)[(size_t)m * ldc + col] = val;
                }
            }
        }
    } else if (MODE == 2) {
        // fallback path only: fused coalesced scatter-add (atomic)
        float* trf = (float*)smem;   // [32][130] f32
#pragma unroll
        for (int pass = 0; pass < 4; ++pass) {
            bar_lgkm();
            if (wm == ((pass >> 1) << 6)) {
                const int i0 = (pass & 1) << 1;
#pragma unroll
                for (int ii = 0; ii < 2; ++ii) {
                    const int i = i0 + ii;
                    const int lr = ii * 16 + l4;
#pragma unroll
                    for (int v = 0; v < 4; ++v) {
#pragma unroll
                        for (int j = 0; j < 4; ++j) {
                            const int cc = wn + j * 16 + l15;
                            float val = acc[i][j][v] + bias[c * 128 + cc];
                            if (relu) val = fmaxf(val, 0.f);
                            trf[(lr + v) * 130 + cc] = val;
                        }
                    }
                }
            }
            bar_lgkm();
            const int ebase = p * 128 + pass * 32;
#pragma unroll
            for (int it = 0; it < 16; ++it) {
                const int id = it * 256 + tid;
                const int lr = id >> 7;
                const int colg = id & 127;
                const int el = ebase + lr;
                if (el < M) {
                    const int node = clampi(srow[el], NN);
                    atomicAdd(&aux[(size_t)node * 512 + c * 128 + colg],
                              trf[lr * 130 + colg]);
                }
            }
        }
    } else if (MODE == 3) {
        const float* mw1 = aux;
        float* out = (float*)C;
#pragma unroll
        for (int i = 0; i < 4; ++i) {
#pragma unroll
            for (int v = 0; v < 4; ++v) {
                const int m = p * 128 + wm + i * 16 + l4 + v;
                const int mc = m < M ? m : M - 1;
                const float* brow = bias + (size_t)clampi(gbid[mc], BB) * ldbias;
                float s = 0.f;
#pragma unroll
                for (int j = 0; j < 4; ++j) {
                    const int col = c * 128 + wn + j * 16 + l15;
                    float val = acc[i][j][v] + brow[col];
                    val = fmaxf(val, 0.f);
                    s += val * mw1[col];
                }
                s += __shfl_down(s, 8, 16);
                s += __shfl_down(s, 4, 16);
                s += __shfl_down(s, 2, 16);
                s += __shfl_down(s, 1, 16);
                if (l15 == 0 && m < M) atomicAdd(&out[m], s);
            }
        }
    } else {
        // MODE 4: row-major f16 out (h_all). Same tr fill as MODE 0; write
        // rows: 16 lanes x 16B = 256B contiguous per row-tile.
        _Float16* tr = (_Float16*)smem;
        _Float16* hout = (_Float16*)C;
#pragma unroll
        for (int pass = 0; pass < 2; ++pass) {
            bar_lgkm();
            if (wm == pass * 64) {
#pragma unroll
                for (int i = 0; i < 4; ++i) {
#pragma unroll
                    for (int v = 0; v < 4; ++v) {
                        const int lr = i * 16 + l4 + v;
#pragma unroll
                        for (int j = 0; j < 4; ++j) {
                            const int cc = wn + j * 16 + l15;
                            float val = acc[i][j][v] + bias[c * 128 + cc];
                            if (relu) val = fmaxf(val, 0.f);
                            tr[lr * 132 + cc] = (_Float16)val;
                        }
                    }
                }
            }
            bar_lgkm();
#pragma unroll
            for (int it = 0; it < 4; ++it) {
                const int id = it * 256 + tid;
                const int cg = id & 15;            // col group of 8
                const int r  = (id >> 4) & 63;
                f16x4 lo = *(const f16x4*)(tr + r * 132 + cg * 8);
                f16x4 hi = *(const f16x4*)(tr + r * 132 + cg * 8 + 4);
                f16x8 v8;
#pragma unroll
                for (int t = 0; t < 4; ++t) { v8[t] = lo[t]; v8[t + 4] = hi[t]; }
                const size_t grow = (size_t)p * 128 + pass * 64 + r;
                *(f16x8*)(hout + grow * 512 + c * 128 + cg * 8) = v8;
            }
        }
    }
}

// ------------------------- helper kernels ----------------------------------

// fp32 -> blocked f16 [N/128][Kd/32].
__global__ void k_w2h_blk(const float* __restrict__ src, _Float16* __restrict__ dst,
                          int N, int Ksrc, int Kd, int mode)
{
    int t = blockIdx.x * blockDim.x + threadIdx.x;
    if (t >= N * Kd) return;
    int n = t / Kd, k = t - n * Kd;
    float v = 0.f;
    if (mode == 0)      { if (k < Ksrc) v = src[(size_t)n * Ksrc + k]; }
    else if (mode == 1) { if (k < 19) v = src[(size_t)n * 275 + k]; }
    else if (mode == 2) { if (k < 9) v = src[(size_t)n * Ksrc + k];
                          else if (k >= 32 && k < 544) v = src[(size_t)n * Ksrc + 9 + (k - 32)]; }
    else if (mode == 4) { if (k < Ksrc) v = src[(size_t)k * N + n]; }
    else                { v = src[(size_t)n * Ksrc + 9 + k]; }
    int KT = Kd >> 5;
    int nt = n >> 7, r = n & 127, kt = k >> 5, kg = (k >> 3) & 3, ko = k & 7;
    dst[(((size_t)nt * KT + kt) * 4 + kg) * 1024 + (size_t)r * 8 + ko] = (_Float16)v;
}

// whnc kt32 slot
__global__ void k_fill_w32(const float* __restrict__ nw0, _Float16* __restrict__ whnc)
{
    int t = blockIdx.x * blockDim.x + threadIdx.x;
    if (t >= 512 * 32) return;
    int n = t >> 5, k = t & 31;
    float v = (k < 9) ? nw0[(size_t)n * 521 + k] : 0.f;
    int nt = n >> 7, r = n & 127, kg = (k >> 3) & 3, ko = k & 7;
    whnc[(((size_t)nt * 33 + 32) * 4 + kg) * 1024 + (size_t)r * 8 + ko] = (_Float16)v;
}

// bfused[n] = dot(nw0[n][9:521], eb4) + nb0[n]
__global__ void k_bfuse(const float* __restrict__ nw0, const float* __restrict__ eb4,
                        const float* __restrict__ nb0, float* __restrict__ bf)
{
    int wave = (blockIdx.x * 256 + threadIdx.x) >> 6;
    int lane = threadIdx.x & 63;
    if (wave >= 512) return;
    const float* wr = nw0 + (size_t)wave * 521 + 9;
    float s = 0.f;
#pragma unroll
    for (int i = 0; i < 8; ++i) s += wr[lane * 8 + i] * eb4[lane * 8 + i];
    for (int off = 32; off; off >>= 1) s += __shfl_down(s, off);
    if (lane == 0) bf[wave] = s + nb0[wave];
}

// u_r[16,256] fp32
__global__ void k_u_r(const float* __restrict__ u, const float* __restrict__ w_sel,
                      const float* __restrict__ b_sel, float* __restrict__ u_r)
{
    int wave = (blockIdx.x * 256 + threadIdx.x) >> 6;
    int lane = threadIdx.x & 63;
    int b = wave >> 8, n = wave & 255;
    const float4* u4 = (const float4*)(u + (size_t)b * 4096);
    const float4* w4 = (const float4*)(w_sel + (size_t)n * 4096);
    float s = 0.f;
    for (int i = lane; i < 1024; i += 64) {
        float4 a = u4[i], c = w4[i];
        s += a.x * c.x + a.y * c.y + a.z * c.z + a.w * c.w;
    }
    for (int off = 32; off; off >>= 1) s += __shfl_down(s, off);
    if (lane == 0) u_r[b * 256 + n] = s + b_sel[n];
}

// ub[16][Nout] = u_r @ w[:, koff:koff+256]^T + b
__global__ void k_graph_bias(const float* __restrict__ u_r, const float* __restrict__ w,
                             const float* __restrict__ b, float* __restrict__ ub,
                             int Nout, int Ksrc, int koff)
{
    int wave = (blockIdx.x * 256 + threadIdx.x) >> 6;
    int lane = threadIdx.x & 63;
    if (wave >= 16 * Nout) return;
    int g = wave / Nout, n = wave - g * Nout;
    const float* ur = u_r + (size_t)g * 256;
    const float* wr = w + (size_t)n * Ksrc + koff;
    float s = 0.f;
#pragma unroll
    for (int i = 0; i < 4; ++i) s += ur[lane * 4 + i] * wr[lane * 4 + i];
    for (int off = 32; off; off >>= 1) s += __shfl_down(s, off);
    if (lane == 0) ub[(size_t)g * Nout + n] = s + b[n];
}

// gbe + per-node edge count in one pass
__global__ void k_gbe(const int* __restrict__ row, const int* __restrict__ batch,
                      int* __restrict__ gbe, float* __restrict__ cnt)
{
    int e = blockIdx.x * blockDim.x + threadIdx.x;
    if (e >= EE) return;
    int r = clampi(row[e], NN);
    gbe[e] = clampi(batch[r], BB);
    atomicAdd(&cnt[r], 1.f);
}

// out[n] = mb1[0]
__global__ void k_init_out(float* __restrict__ out, const float* __restrict__ mb1)
{
    int t = blockIdx.x * blockDim.x + threadIdx.x;
    if (t < NN) out[t] = mb1[0];
}

// CSR: exclusive prefix sum of (int)cnt over NN nodes. 1 block x 1024 thr.
__global__ void k_scan(const float* __restrict__ cnt, int* __restrict__ ptr,
                       int* __restrict__ cur)
{
    __shared__ int part[1024];
    const int t = threadIdx.x;
    const int PER = (NN + 1023) / 1024;   // 20
    const int base = t * PER;
    int s = 0;
    for (int i = 0; i < PER; ++i) {
        int n = base + i;
        if (n < NN) s += (int)cnt[n];
    }
    part[t] = s;
    __syncthreads();
    for (int off = 1; off < 1024; off <<= 1) {
        int v = (t >= off) ? part[t - off] : 0;
        __syncthreads();
        part[t] += v;
        __syncthreads();
    }
    int run = (t == 0) ? 0 : part[t - 1];
    for (int i = 0; i < PER; ++i) {
        int n = base + i;
        if (n < NN) {
            ptr[n] = run;
            cur[n] = run;
            run += (int)cnt[n];
        }
    }
    if (t == 1023) ptr[NN] = part[1023];
}

// CSR fill: place edge ids into per-node lists
__global__ void k_csr_fill(const int* __restrict__ row, int* __restrict__ cur,
                           int* __restrict__ idx)
{
    int e = blockIdx.x * blockDim.x + threadIdx.x;
    if (e >= EE) return;
    int r = clampi(row[e], NN);
    int pos = atomicAdd(&cur[r], 1);
    idx[pos] = e;
}

// CSR gather + mean + m_in write (block per node, thread per 2 cols).
// Also fills kt0 (x cols). Replaces atomic scatter + k_gather_min + agg.
__global__ void k_gather_csr(const float* __restrict__ x, const _Float16* __restrict__ h,
                             const int* __restrict__ ptr, const int* __restrict__ idx,
                             const float* __restrict__ cnt, _Float16* __restrict__ dst)
{
    const int n = blockIdx.x;
    const int t = threadIdx.x;
    const int base = ptr[n];
    const int deg = (int)cnt[n];
    const int c0 = 2 * t;
    float s0 = 0.f, s1 = 0.f;
    for (int d = 0; d < deg; ++d) {
        const int e = idx[base + d];
        f16x2 hv = *(const f16x2*)(h + (size_t)e * 512 + c0);
        s0 += (float)hv[0];
        s1 += (float)hv[1];
    }
    const float inv = 1.f / fmaxf(cnt[n], 1.f);
    const int mt = n >> 7, r = n & 127;
    const int kt = 1 + (c0 >> 5), kg = (c0 >> 3) & 3, ko = c0 & 7;
    _Float16* dp = dst + (((size_t)mt * 17 + kt) * 4 + kg) * 1024 + (size_t)r * 8 + ko;
    f16x2 o; o[0] = (_Float16)(s0 * inv); o[1] = (_Float16)(s1 * inv);
    *(f16x2*)dp = o;
    if (t < 16) {
        const int cx = 2 * t;
        f16x2 vx;
        vx[0] = (_Float16)(cx < 9 ? x[(size_t)n * 9 + cx] : 0.f);
        vx[1] = (_Float16)(cx + 1 < 9 ? x[(size_t)n * 9 + cx + 1] : 0.f);
        const int kg0 = (cx >> 3) & 3, ko0 = cx & 7;
        _Float16* d0 = dst + ((size_t)mt * 17 * 4 + kg0) * 1024 + (size_t)r * 8 + ko0;
        *(f16x2*)d0 = vx;
    }
}

// edge gather (unchanged)
__global__ void k_gather_edge_blk(const float* __restrict__ x, const float* __restrict__ ea,
                                  const int* __restrict__ row, const int* __restrict__ col,
                                  _Float16* __restrict__ dst, _Float16* __restrict__ pong,
                                  int e0, int ec, int MTR)
{
    int t = blockIdx.x * blockDim.x + threadIdx.x;
    if (t >= MTR * 4) return;
    int r = t >> 2, kg = t & 3;
    int e = e0 + r; int emax = e0 + ec - 1;
    if (e > emax) e = emax;
    int ri = clampi(row[e], NN), ci = clampi(col[e], NN);
    f16x8 v;
    f16x8 vx = (f16x8)(_Float16)0.f;
#pragma unroll
    for (int j = 0; j < 8; ++j) {
        int cc = kg * 8 + j;
        float fv = 0.f;
        if (cc < 9)       fv = x[(size_t)ri * 9 + cc];
        else if (cc < 18) fv = x[(size_t)ci * 9 + (cc - 9)];
        else if (cc == 18) fv = ea[e];
        v[j] = (_Float16)fv;
        if (cc < 9) vx[j] = (_Float16)x[(size_t)ci * 9 + cc];
    }
    *(f16x8*)(dst + (size_t)(r >> 7) * 4096 + (size_t)kg * 1024 + (size_t)(r & 127) * 8) = v;
    *(f16x8*)(pong + (((size_t)(r >> 7) * 33 + 32) * 4 + kg) * 1024 + (size_t)(r & 127) * 8) = vx;
}

// m_in gather from agg (fallback path only)
__global__ void k_gather_min(const float* __restrict__ x, const float* __restrict__ agg,
                             const float* __restrict__ cnt, _Float16* __restrict__ dst, int MTR)
{
    int t = blockIdx.x * blockDim.x + threadIdx.x;
    if (t >= MTR * 68) return;
    int r = t / 68, q = t - r * 68;
    int kt = q >> 2, kg = q & 3;
    int n = r < NN ? r : NN - 1;
    f16x8 v = (f16x8)(_Float16)0.f;
    if (kt == 0) {
#pragma unroll
        for (int j = 0; j < 8; ++j) {
            int cc = kg * 8 + j;
            if (cc < 9) v[j] = (_Float16)x[(size_t)n * 9 + cc];
        }
    } else {
        float inv = 1.f / fmaxf(cnt[n], 1.f);
        int cbase = (kt - 1) * 32 + kg * 8;
        const float4* ap = (const float4*)(agg + (size_t)n * 512 + cbase);
        float4 a0 = ap[0], a1 = ap[1];
        v[0] = (_Float16)(a0.x * inv); v[1] = (_Float16)(a0.y * inv);
        v[2] = (_Float16)(a0.z * inv); v[3] = (_Float16)(a0.w * inv);
        v[4] = (_Float16)(a1.x * inv); v[5] = (_Float16)(a1.y * inv);
        v[6] = (_Float16)(a1.z * inv); v[7] = (_Float16)(a1.w * inv);
    }
    *(f16x8*)(dst + ((size_t)(r >> 7) * 17 + kt) * 4096 + (size_t)kg * 1024 + (size_t)(r & 127) * 8) = v;
}

// ------------------------------- host --------------------------------------

#define GRID1(n) dim3(((n) + 255) / 256)

static inline void gemmB0(hipStream_t s, const _Float16* A, const _Float16* Wt, int KT, int KTs,
                          const float* bias, int ldbias, const int* gbid,
                          void* C, int KTo, int ktOff,
                          int M, int MT, int NT, int relu)
{
    hipLaunchKernelGGL(gemm_blk<0>, dim3(NT, MT), dim3(256), 0, s,
                       A, Wt, KT, KTs, bias, ldbias, gbid, C, KTo, ktOff, 0,
                       nullptr, nullptr, M, relu);
}
static inline void gemmB2(hipStream_t s, const _Float16* A, const _Float16* Wt, int KT, int KTs,
                          const float* bias, const int* srow, float* agg,
                          int M, int MT, int NT, int relu)
{
    hipLaunchKernelGGL(gemm_blk<2>, dim3(NT, MT), dim3(256), 0, s,
                       A, Wt, KT, KTs, bias, 0, nullptr, nullptr, 0, 0, 0,
                       srow, agg, M, relu);
}
static inline void gemmB3(hipStream_t s, const _Float16* A, const _Float16* Wt, int KT, int KTs,
                          const float* bias, int ldbias, const int* gbid,
                          float* out, const float* mw1,
                          int M, int MT, int NT)
{
    hipLaunchKernelGGL(gemm_blk<3>, dim3(NT, MT), dim3(256), 0, s,
                       A, Wt, KT, KTs, bias, ldbias, gbid, out, 0, 0, 0,
                       nullptr, (float*)mw1, M, 1);
}
static inline void gemmB4(hipStream_t s, const _Float16* A, const _Float16* Wt, int KT, int KTs,
                          const float* bias, _Float16* hout, int M, int MT, int NT)
{
    hipLaunchKernelGGL(gemm_blk<4>, dim3(NT, MT), dim3(256), 0, s,
                       A, Wt, KT, KTs, bias, 0, nullptr, hout, 0, 0, 0,
                       nullptr, nullptr, M, 1);
}

extern "C" void kernel_launch(void* const* d_in, const int* in_sizes, int n_in,
                              void* d_out, int out_size, void* d_ws, size_t ws_size,
                              hipStream_t stream)
{
    const float* x     = (const float*)d_in[0];
    const int*   ei    = (const int*)d_in[1];
    const float* ea    = (const float*)d_in[2];
    const float* u     = (const float*)d_in[3];
    const int*   batch = (const int*)d_in[4];
    const float* w_sel = (const float*)d_in[5];
    const float* b_sel = (const float*)d_in[6];
    const float* ew0 = (const float*)d_in[7];   const float* eb0 = (const float*)d_in[8];
    const float* ew1 = (const float*)d_in[9];   const float* eb1 = (const float*)d_in[10];
    const float* ew2 = (const float*)d_in[11];  const float* eb2 = (const float*)d_in[12];
    const float* ew3 = (const float*)d_in[13];  const float* eb3 = (const float*)d_in[14];
    const float* ew4 = (const float*)d_in[15];  const float* eb4 = (const float*)d_in[16];
    const float* nw0 = (const float*)d_in[17];  const float* nb0 = (const float*)d_in[18];
    const float* nw1 = (const float*)d_in[19];  const float* nb1 = (const float*)d_in[20];
    const float* mw0 = (const float*)d_in[21];  const float* mb0 = (const float*)d_in[22];
    const float* mw1 = (const float*)d_in[23];  const float* mb1 = (const float*)d_in[24];

    const int* row = ei;
    const int* col = ei + EE;

    const int MTm = (NN + 127) / 128;           // 157
    const size_t EEp = 100352;                  // 784*128 >= EE padded rows

    // ---- size planning (pure fn of ws_size -> capture-safe) ----
    auto alsz = [](size_t b) { return (b + 255) & ~(size_t)255; };
    const size_t commonB =
        alsz(20000 * 4) + alsz(1024 * 4) + alsz(16 * 256 * 4) + alsz(16 * 1024 * 4) +
        alsz(16 * 512 * 4) + alsz(512 * 4) + alsz((size_t)EE * 4) +
        alsz((size_t)8 * 4096 * 2) + 3 * alsz((size_t)8 * 32 * 4096 * 2) +
        alsz((size_t)4 * 33 * 4096 * 2) + alsz((size_t)4 * 16 * 4096 * 2) +
        alsz((size_t)4 * 17 * 4096 * 2) + alsz((size_t)4 * 16 * 4096 * 2) +
        alsz((size_t)8 * 16 * 4096 * 2) + alsz((size_t)MTm * 17 * 4096 * 2);
    const size_t aggB = alsz((size_t)NN * 512 * 4);
    const size_t csrB = alsz((NN + 2) * 4) + alsz((size_t)NN * 4) +
                        alsz((size_t)EE * 4) + alsz(EEp * 512 * 2);
    auto chB = [&](int ec) {
        size_t Mr = (size_t)((ec + 255) / 256) * 256;
        return alsz(Mr * 64) + 2 * alsz(Mr * 2112);
    };
    const bool csrPath = (commonB + csrB + chB(32768) + 8192 <= ws_size);
    int EC = 5000;
    if (csrPath) EC = 32768;
    else {
        static const int ecOpts[] = {32768, 25000, 12500, 10000, 5000};
        for (int i = 0; i < 5; ++i) {
            if (commonB + aggB + chB(ecOpts[i]) + 8192 <= ws_size) { EC = ecOpts[i]; break; }
        }
    }
    const bool big = (EC == 32768);

    // ---- allocation ----
    char* W = (char*)d_ws;
    size_t off = 0;
    auto alloc = [&](size_t bytes) -> char* {
        char* p = W + off;
        off = (off + bytes + 255) & ~(size_t)255;
        return p;
    };
    float* cnt = (float*)alloc(20000 * 4);
    float* agg = nullptr;
    if (!csrPath) agg = (float*)alloc((size_t)NN * 512 * 4);
    float* zbias = (float*)alloc(1024 * 4);             // stays zero
    const size_t zeroBytes = off;
    float*    u_r  = (float*)alloc(16 * 256 * 4);
    float*    ub0  = (float*)alloc(16 * 1024 * 4);
    float*    ubm  = (float*)alloc(16 * 512 * 4);
    float*    bfu  = (float*)alloc(512 * 4);
    int*      gbe  = (int*)alloc((size_t)EE * 4);
    _Float16* wh0   = (_Float16*)alloc((size_t)8 * 1 * 4096 * 2);
    _Float16* wh1   = (_Float16*)alloc((size_t)8 * 32 * 4096 * 2);
    _Float16* wh2   = (_Float16*)alloc((size_t)8 * 32 * 4096 * 2);
    _Float16* wh3   = (_Float16*)alloc((size_t)8 * 32 * 4096 * 2);
    _Float16* whnc  = (_Float16*)alloc((size_t)4 * 33 * 4096 * 2);
    _Float16* whn1  = (_Float16*)alloc((size_t)4 * 16 * 4096 * 2);
    _Float16* whm0  = (_Float16*)alloc((size_t)4 * 17 * 4096 * 2);
    _Float16* nw0eoB= (_Float16*)alloc((size_t)4 * 16 * 4096 * 2);
    _Float16* ew4T  = (_Float16*)alloc((size_t)8 * 16 * 4096 * 2);
    _Float16* m_in  = (_Float16*)alloc((size_t)MTm * 17 * 4096 * 2);
    int*      csr_ptr = nullptr; int* csr_cur = nullptr; int* csr_idx = nullptr;
    _Float16* h_all = nullptr;
    if (csrPath) {
        csr_ptr = (int*)alloc((NN + 2) * 4);
        csr_cur = (int*)alloc((size_t)NN * 4);
        csr_idx = (int*)alloc((size_t)EE * 4);
        h_all   = (_Float16*)alloc(EEp * 512 * 2);
    }
    const size_t MTR = (size_t)((EC + 255) / 256) * 256;
    _Float16* e_in = (_Float16*)alloc(MTR * 64);
    _Float16* ping = (_Float16*)alloc(MTR * 2112);
    _Float16* pong = (_Float16*)alloc(MTR * 2112);
    const int NCH = (EE + EC - 1) / EC;

    (void)hipMemsetAsync(W, 0, zeroBytes, stream);
    hipLaunchKernelGGL(k_init_out, GRID1(NN), dim3(256), 0, stream, (float*)d_out, mb1);

    hipLaunchKernelGGL(k_u_r, dim3(1024), dim3(256), 0, stream, u, w_sel, b_sel, u_r);
    hipLaunchKernelGGL(k_graph_bias, GRID1(16 * 1024 * 64), dim3(256), 0, stream,
                       u_r, ew0, eb0, ub0, 1024, 275, 19);
    hipLaunchKernelGGL(k_graph_bias, GRID1(16 * 512 * 64), dim3(256), 0, stream,
                       u_r, mw0, mb0, ubm, 512, 777, 521);
    hipLaunchKernelGGL(k_gbe, GRID1(EE), dim3(256), 0, stream, row, batch, gbe, cnt);
    hipLaunchKernelGGL(k_bfuse, dim3(128), dim3(256), 0, stream, nw0, eb4, nb0, bfu);
    if (csrPath) {
        hipLaunchKernelGGL(k_scan, dim3(1), dim3(1024), 0, stream, cnt, csr_ptr, csr_cur);
        hipLaunchKernelGGL(k_csr_fill, GRID1(EE), dim3(256), 0, stream, row, csr_cur, csr_idx);
    }

    auto pack = [&](const float* w, _Float16* wh, int N, int Ksrc, int Kd, int mode) {
        hipLaunchKernelGGL(k_w2h_blk, GRID1(N * Kd), dim3(256), 0, stream, w, wh, N, Ksrc, Kd, mode);
    };
    pack(ew0, wh0, 1024, 275, 32, 1);
    pack(ew1, wh1, 1024, 1024, 1024, 0);
    pack(ew2, wh2, 1024, 1024, 1024, 0);
    pack(ew3, wh3, 1024, 1024, 1024, 0);
    pack(nw1, whn1, 512, 512, 512, 0);
    pack(mw0, whm0, 512, 777, 544, 2);
    pack(nw0, nw0eoB, 512, 521, 512, 5);
    pack(ew4, ew4T, 1024, 512, 512, 4);
    // W_comb = nw0eo @ ew4 -> whnc kt 0..31 (blocked out)
    gemmB0(stream, nw0eoB, ew4T, 16, 16, zbias, 0, nullptr, whnc, 33, 0, 512, 4, 8, 0);
    hipLaunchKernelGGL(k_fill_w32, GRID1(512 * 32), dim3(256), 0, stream, nw0, whnc);

    for (int ch = 0; ch < NCH; ++ch) {
        int e0 = ch * EC;
        int ec = EC; if (e0 + ec > EE) ec = EE - e0;
        const int ecr  = ((ec + 255) / 256) * 256;
        const int MTc  = ecr / 128;
        const int MT2c = ecr / 256;
        hipLaunchKernelGGL(k_gather_edge_blk, GRID1(ecr * 4), dim3(256), 0, stream,
                           x, ea, row, col, e_in, pong, e0, ec, ecr);
        gemmB0(stream, e_in, wh0, 1, 1, ub0, 1024, gbe + e0, ping, 33, 0, ec, MTc, 8, 1);
        auto wideL = [&](const _Float16* Ain, const _Float16* Wt,
                         const float* b, _Float16* Cout) {
            if (big)
                hipLaunchKernelGGL(gemm256h, dim3(8, MT2c), dim3(256), 0, stream,
                                   Ain, Wt, 32, 33, b, Cout, 33, 0);
            else
                hipLaunchKernelGGL(gemmAD, dim3(8, MTc), dim3(256), 0, stream,
                                   Ain, Wt, 32, 33, b, Cout, 33, 0);
        };
        wideL(ping, wh1, eb1, pong);
        wideL(pong, wh2, eb2, ping);
        wideL(ping, wh3, eb3, pong);
        // nc: fused (ew4+nw0) GEMM, K=1056, KT=33 (odd tail in gemmAD)
        hipLaunchKernelGGL(gemmAD, dim3(4, MTc), dim3(256), 0, stream,
                           pong, whnc, 33, 33, bfu, ping, 16, 0);
        // n1
        if (csrPath)
            gemmB4(stream, ping, whn1, 16, 16, nb1, h_all + (size_t)e0 * 512, ec, MTc, 4);
        else
            gemmB2(stream, ping, whn1, 16, 16, nb1, row + e0, agg, ec, MTc, 4, 1);
    }

    if (csrPath) {
        hipLaunchKernelGGL(k_gather_csr, dim3(NN), dim3(256), 0, stream,
                           x, h_all, csr_ptr, csr_idx, cnt, m_in);
    } else {
        hipLaunchKernelGGL(k_gather_min, GRID1((int)(MTm * 128) * 68), dim3(256), 0, stream,
                           x, agg, cnt, m_in, MTm * 128);
    }
    // m0 + final fused (mode 3)
    gemmB3(stream, m_in, whm0, 17, 17, ubm, 512, batch, (float*)d_out, mw1, NN, MTm, 4);
}

// Round 11
// 1355.074 us; speedup vs baseline: 1.0495x; 1.0294x over previous
//
#include <hip/hip_runtime.h>

// ---------------------------------------------------------------------------
// OGRENet GraphNet block — f16 MFMA, BLOCKED operands.
// Blocked layout (f16): offset(m,k) = ((mt*KTo + kt)*4 + kg)*1024 + r*8 + ko
// R12: ew4+nw0 folded; R13: k_final folded into m0 (MODE=3).
// R18: EC=32768 full-fill. R19: read-12-frags + 1 barrier/phase.
// R21: gemm256h 4-wave 256x128, 2 blk/CU — WIN 1381us. Top cost -> n1
//      atomic scatter (73us x4). R22: lgkm-only barriers: n1 UNCHANGED ->
//      n1 is raw atomic-RMW-throughput-bound (agg 41MB > L2).
// R23: CSR plan NEVER RAN — needed 276MB, ws in [214, 276) -> fallback.
// R24: CSR sized to fit: EC=16384 in CSR path only -> ping/pong 69.2MB,
//      total ~206MB < 214MB (known fit). Wide grid 8x64 = 512 blocks =
//      EXACTLY 1.00 round @2blk/CU; l0 1024 blocks = 1.00 round @4blk/CU.
//      k_gather_csr now prefetches idx tile into LDS (breaks serial
//      idx->h dependency). h f16-rounding error adds in quadrature with
//      existing m_in f16 quantization (~+10%). Fallback = R22 unchanged.
// [R8: template MODE; R7: rocprof replay overstates atomic kernels ~20x.]
// ---------------------------------------------------------------------------

#define NN 20000
#define EE 100000
#define BB 16

typedef _Float16 f16x8 __attribute__((ext_vector_type(8)));
typedef _Float16 f16x4 __attribute__((ext_vector_type(4)));
typedef _Float16 f16x2 __attribute__((ext_vector_type(2)));
typedef float f32x4 __attribute__((ext_vector_type(4)));

__device__ __forceinline__ int clampi(int v, int hi) {
    return v < 0 ? 0 : (v >= hi ? hi - 1 : v);
}

__device__ __forceinline__ void gld_lds16(const void* g, void* l) {
    __builtin_amdgcn_global_load_lds(
        (const __attribute__((address_space(1))) unsigned int*)g,
        (__attribute__((address_space(3))) unsigned int*)l, 16, 0, 0);
}

// barrier that orders LDS (lgkm) but lets VMEM stores/atomics stay in flight
__device__ __forceinline__ void bar_lgkm() {
    asm volatile("s_waitcnt lgkmcnt(0)" ::: "memory");
    __builtin_amdgcn_s_barrier();
}

// -------- 256x128-tile 4-wave GEMM, 2 regions, 2 blocks/CU (R21) -----------
__global__ __launch_bounds__(256, 2) void gemm256h(
    const _Float16* __restrict__ Ag, const _Float16* __restrict__ Wt,
    int KT, int KTs, const float* __restrict__ bias,
    _Float16* __restrict__ C, int KTo, int ktOff)
{
    __shared__ _Float16 smem[24576];   // 2 regions x (A 8192 + B 4096) f16

    const int tid  = threadIdx.x;
    const int lane = tid & 63;
    const int wid  = tid >> 6;       // 0..3
    const int wm   = wid & 1;        // row page (128 rows)
    const int wn   = wid >> 1;       // col half (64 cols)
    const int l15  = lane & 15;
    const int l4   = (lane >> 4) << 2;
    const int kq   = (lane >> 4) << 10;

    const int nb  = gridDim.x;       // 8
    const int MT2 = gridDim.y;
    int f = blockIdx.y * nb + blockIdx.x;
    const int MT8 = MT2 & ~7;
    int p, c;
    if (f < MT8 * nb) {
        c = (f >> 3) % nb;
        p = (f & 7) + 8 * ((f >> 3) / nb);
    } else {
        int g = f - MT8 * nb;
        p = MT8 + g / nb;
        c = g % nb;
    }

    const int S = KT;                // phases; gemm256h only sees even S
    auto stage = [&](int ph) {
        const _Float16* gA0 = Ag + ((size_t)(2 * p)     * KTs + ph) * 4096 + tid * 8;
        const _Float16* gA1 = Ag + ((size_t)(2 * p + 1) * KTs + ph) * 4096 + tid * 8;
        const _Float16* gB  = Wt + ((size_t)c * KT + ph) * 4096 + tid * 8;
        _Float16* rA = smem + (ph & 1) * 12288;
        _Float16* rB = rA + 8192;
        gld_lds16(gA0,        rA + wid * 512);
        gld_lds16(gA0 + 2048, rA + 2048 + wid * 512);
        gld_lds16(gA1,        rA + 4096 + wid * 512);
        gld_lds16(gA1 + 2048, rA + 6144 + wid * 512);
        gld_lds16(gB,         rB + wid * 512);
        gld_lds16(gB + 2048,  rB + 2048 + wid * 512);
    };

    f32x4 acc[8][4];
#pragma unroll
    for (int i = 0; i < 8; ++i)
#pragma unroll
        for (int j = 0; j < 4; ++j) acc[i][j] = (f32x4){0.f, 0.f, 0.f, 0.f};

    stage(0);

    for (int s = 0; s < S; ++s) {
        asm volatile("s_waitcnt vmcnt(0)" ::: "memory");
        __builtin_amdgcn_s_barrier();
        if (s + 1 < S) stage(s + 1);
        const _Float16* rA = smem + (s & 1) * 12288;
        const _Float16* rB = rA + 8192;
        const _Float16* Ap = rA + wm * 4096 + kq + l15 * 8;
        const _Float16* Bp = rB + kq + wn * 512 + l15 * 8;
        f16x8 af[8], bf[4];
#pragma unroll
        for (int j = 0; j < 4; ++j) bf[j] = *(const f16x8*)(Bp + j * 128);
#pragma unroll
        for (int i = 0; i < 8; ++i) af[i] = *(const f16x8*)(Ap + i * 128);
        __builtin_amdgcn_s_setprio(1);
#pragma unroll
        for (int i = 0; i < 8; ++i)
#pragma unroll
            for (int j = 0; j < 4; ++j)
                acc[i][j] = __builtin_amdgcn_mfma_f32_16x16x32_f16(
                    af[i], bf[j], acc[i][j], 0, 0, 0);
        __builtin_amdgcn_s_setprio(0);
    }

    // epilogue: 4 passes of 64 rows; tr = [64][132] f16
    _Float16* tr = smem;
#pragma unroll
    for (int pass = 0; pass < 4; ++pass) {
        bar_lgkm();
        if (wm == (pass >> 1)) {
            const int fi = (pass & 1) << 2;
#pragma unroll
            for (int i = 0; i < 4; ++i) {
#pragma unroll
                for (int v = 0; v < 4; ++v) {
                    const int lr = i * 16 + l4 + v;
#pragma unroll
                    for (int j = 0; j < 4; ++j) {
                        const int cc = wn * 64 + j * 16 + l15;
                        float val = acc[fi + i][j][v] + bias[c * 128 + cc];
                        val = fmaxf(val, 0.f);
                        tr[lr * 132 + cc] = (_Float16)val;
                    }
                }
            }
        }
        bar_lgkm();
#pragma unroll
        for (int it = 0; it < 4; ++it) {
            const int id = it * 256 + tid;
            const int r  = id & 63;
            const int cg = id >> 6;        // 0..15 (128 cols)
            f16x4 lo = *(const f16x4*)(tr + r * 132 + cg * 8);
            f16x4 hi = *(const f16x4*)(tr + r * 132 + cg * 8 + 4);
            f16x8 v8;
#pragma unroll
            for (int t = 0; t < 4; ++t) { v8[t] = lo[t]; v8[t + 4] = hi[t]; }
            const int kti = ktOff + (c << 2) + (cg >> 2);
            const int mt_out = 2 * p + (pass >> 1);
            const int r128 = ((pass & 1) << 6) + r;
            *(f16x8*)(C + (((size_t)mt_out * KTo + kti) * 4 + (cg & 3)) * 1024
                        + (size_t)r128 * 8) = v8;
        }
    }
}

// ------------- 128x128 A-in-LDS-ring / B-direct GEMM (R16, verified) -------
__global__ __launch_bounds__(256, 3) void gemmAD(
    const _Float16* __restrict__ Ag, const _Float16* __restrict__ Wt,
    int KT, int KTs, const float* __restrict__ bias,
    _Float16* __restrict__ C, int KTo, int ktOff)
{
    __shared__ _Float16 As[16384];   // 4-slot ring x 4096 f16 = 32 KB

    const int tid  = threadIdx.x;
    const int lane = tid & 63;
    const int wid  = tid >> 6;
    const int wm = (wid & 1) << 6;
    const int wn = (wid >> 1) << 6;
    const int l15 = lane & 15;
    const int l4  = (lane >> 4) << 2;
    const int kg  = (lane >> 4) << 10;

    const int nb = gridDim.x;
    const int MT = gridDim.y;
    int f = blockIdx.y * nb + blockIdx.x;
    const int MT8 = MT & ~7;
    int p, c;
    if (f < MT8 * nb) {
        c = (f >> 3) % nb;
        p = (f & 7) + 8 * ((f >> 3) / nb);
    } else {
        int g = f - MT8 * nb;
        p = MT8 + g / nb;
        c = g % nb;
    }

    f32x4 acc[4][4];
#pragma unroll
    for (int i = 0; i < 4; ++i)
#pragma unroll
        for (int j = 0; j < 4; ++j) acc[i][j] = (f32x4){0.f, 0.f, 0.f, 0.f};

    const _Float16* gA = Ag + (size_t)p * KTs * 4096;
    const _Float16* gB = Wt + ((size_t)c * KT) * 4096 + kg + (wn + l15) * 8;
    const int ktLim = KT - 1;

    auto stageA = [&](int ktA) {
        const _Float16* s = gA + (size_t)ktA * 4096 + tid * 8;
        _Float16* d = As + ((ktA & 3) << 12) + wid * 512;
        gld_lds16(s, d);
        gld_lds16(s + 2048, d + 2048);
    };

    f16x8 bfA[4], bfB[4];
    auto loadB = [&](f16x8 (&bf)[4], int ktB) {
        const _Float16* bp = gB + (size_t)ktB * 4096;
#pragma unroll
        for (int j = 0; j < 4; ++j) bf[j] = *(const f16x8*)(bp + j * 128);
    };

    stageA(0);
    stageA(1 <= ktLim ? 1 : ktLim);
    loadB(bfA, 0);

    auto body = [&](int kt, f16x8 (&cur)[4], f16x8 (&nxt)[4]) {
        const int ktB = kt + 1 <= ktLim ? kt + 1 : ktLim;
        const int ktA = kt + 2 <= ktLim ? kt + 2 : ktLim;
        loadB(nxt, ktB);
        stageA(ktA);
        asm volatile("s_waitcnt vmcnt(12)" ::: "memory");
        __builtin_amdgcn_s_barrier();
        asm volatile("" ::: "memory");
        const _Float16* Ap = As + ((kt & 3) << 12) + kg + (wm + l15) * 8;
        f16x8 af[4];
#pragma unroll
        for (int i = 0; i < 4; ++i) af[i] = *(const f16x8*)(Ap + i * 128);
        __builtin_amdgcn_s_setprio(1);
#pragma unroll
        for (int i = 0; i < 4; ++i)
#pragma unroll
            for (int j = 0; j < 4; ++j)
                acc[i][j] = __builtin_amdgcn_mfma_f32_16x16x32_f16(
                    af[i], cur[j], acc[i][j], 0, 0, 0);
        __builtin_amdgcn_s_setprio(0);
    };

    for (int kt = 0; kt + 2 <= KT; kt += 2) {
        body(kt,     bfA, bfB);
        body(kt + 1, bfB, bfA);
    }
    if (KT & 1) body(KT - 1, bfA, bfB);   // odd-KT tail (nc: KT=33)

    // epilogue: first barrier FULL drain (<=12 gld_lds writes outstanding
    // into As = tr); later barriers lgkm-only.
    _Float16* tr = As;
#pragma unroll
    for (int pass = 0; pass < 2; ++pass) {
        if (pass == 0) __syncthreads(); else bar_lgkm();
        if (wm == pass * 64) {
#pragma unroll
            for (int i = 0; i < 4; ++i) {
#pragma unroll
                for (int v = 0; v < 4; ++v) {
                    const int lr = i * 16 + l4 + v;
#pragma unroll
                    for (int j = 0; j < 4; ++j) {
                        const int cc = wn + j * 16 + l15;
                        float val = acc[i][j][v] + bias[c * 128 + cc];
                        val = fmaxf(val, 0.f);
                        tr[lr * 132 + cc] = (_Float16)val;
                    }
                }
            }
        }
        bar_lgkm();
#pragma unroll
        for (int it = 0; it < 4; ++it) {
            const int id = it * 256 + tid;
            const int r  = id & 63;
            const int cg = id >> 6;
            f16x4 lo = *(const f16x4*)(tr + r * 132 + cg * 8);
            f16x4 hi = *(const f16x4*)(tr + r * 132 + cg * 8 + 4);
            f16x8 v8;
#pragma unroll
            for (int t = 0; t < 4; ++t) { v8[t] = lo[t]; v8[t + 4] = hi[t]; }
            const int kti = ktOff + (c << 2) + (cg >> 2);
            const int gr  = pass * 64 + r;
            size_t o = (((size_t)p * KTo + kti) * 4 + (cg & 3)) * 1024 + (size_t)gr * 8;
            *(f16x8*)(C + o) = v8;
        }
    }
}

// ------------------------- blocked f16 MFMA GEMM (128-path) ----------------
// MODE 0: blocked f16 out; 1: f32 row-major; 2: atomic scatter-add (fallback
// path); 3: fused final dot; 4: ROW-MAJOR f16 out (h_all for CSR gather).
template <int MODE>
__global__ __launch_bounds__(256, 4) void gemm_blk(
    const _Float16* __restrict__ A,      // blocked [MT][KTs]
    const _Float16* __restrict__ Wt,     // blocked [NT][KT] (dense)
    int KT, int KTs,
    const float* __restrict__ bias, int ldbias, const int* __restrict__ gbid,
    void* __restrict__ C, int KTo, int ktOff,
    int ldc,
    const int* __restrict__ srow, float* __restrict__ aux,
    int M, int relu)
{
    __shared__ char smem[32768];
    _Float16* As = (_Float16*)smem;          // 8192 f16
    _Float16* Bs = As + 8192;

    const int tid  = threadIdx.x;
    const int lane = tid & 63;
    const int wid  = tid >> 6;
    const int wm = (wid & 1) << 6;
    const int wn = (wid >> 1) << 6;

    const int nb = gridDim.x;
    const int MT = gridDim.y;
    int f = blockIdx.y * nb + blockIdx.x;
    const int MT8 = MT & ~7;
    int p, c;
    if (f < MT8 * nb) {
        c = (f >> 3) % nb;
        p = (f & 7) + 8 * ((f >> 3) / nb);
    } else {
        int g = f - MT8 * nb;
        p = MT8 + g / nb;
        c = g % nb;
    }

    f32x4 acc[4][4];
#pragma unroll
    for (int i = 0; i < 4; ++i)
#pragma unroll
        for (int j = 0; j < 4; ++j) acc[i][j] = (f32x4){0.f, 0.f, 0.f, 0.f};

    const _Float16* pA = A + (size_t)p * KTs * 4096;
    const _Float16* pB = Wt + (size_t)c * KT * 4096;
    const int cb0 = wid * 64;
    const int cb1 = 256 + wid * 64;
    const int kq  = (lane >> 4) * 128;
    const int l15 = lane & 15;
    const int l4  = (lane >> 4) << 2;

    int kt = 0;
    for (; kt + 2 <= KT; kt += 2) {
        __syncthreads();
        gld_lds16(pA + (size_t)(cb0 + lane) * 8,        As + cb0 * 8);
        gld_lds16(pA + (size_t)(cb1 + lane) * 8,        As + cb1 * 8);
        gld_lds16(pA + 4096 + (size_t)(cb0 + lane) * 8, As + 4096 + cb0 * 8);
        gld_lds16(pA + 4096 + (size_t)(cb1 + lane) * 8, As + 4096 + cb1 * 8);
        gld_lds16(pB + (size_t)(cb0 + lane) * 8,        Bs + cb0 * 8);
        gld_lds16(pB + (size_t)(cb1 + lane) * 8,        Bs + cb1 * 8);
        gld_lds16(pB + 4096 + (size_t)(cb0 + lane) * 8, Bs + 4096 + cb0 * 8);
        gld_lds16(pB + 4096 + (size_t)(cb1 + lane) * 8, Bs + 4096 + cb1 * 8);
        pA += 8192; pB += 8192;
        __syncthreads();

#pragma unroll
        for (int s = 0; s < 2; ++s) {
            f16x8 af[4], bf[4];
            const int sb = s * 4096;
#pragma unroll
            for (int i = 0; i < 4; ++i)
                af[i] = *(const f16x8*)(As + sb + (size_t)((kq + wm + i * 16 + l15) << 3));
#pragma unroll
            for (int j = 0; j < 4; ++j)
                bf[j] = *(const f16x8*)(Bs + sb + (size_t)((kq + wn + j * 16 + l15) << 3));
#pragma unroll
            for (int i = 0; i < 4; ++i)
#pragma unroll
                for (int j = 0; j < 4; ++j)
                    acc[i][j] = __builtin_amdgcn_mfma_f32_16x16x32_f16(af[i], bf[j], acc[i][j], 0, 0, 0);
        }
    }
    if (kt < KT) {
        __syncthreads();
        gld_lds16(pA + (size_t)(cb0 + lane) * 8, As + cb0 * 8);
        gld_lds16(pA + (size_t)(cb1 + lane) * 8, As + cb1 * 8);
        gld_lds16(pB + (size_t)(cb0 + lane) * 8, Bs + cb0 * 8);
        gld_lds16(pB + (size_t)(cb1 + lane) * 8, Bs + cb1 * 8);
        __syncthreads();
        f16x8 af[4], bf[4];
#pragma unroll
        for (int i = 0; i < 4; ++i)
            af[i] = *(const f16x8*)(As + (size_t)((kq + wm + i * 16 + l15) << 3));
#pragma unroll
        for (int j = 0; j < 4; ++j)
            bf[j] = *(const f16x8*)(Bs + (size_t)((kq + wn + j * 16 + l15) << 3));
#pragma unroll
        for (int i = 0; i < 4; ++i)
#pragma unroll
            for (int j = 0; j < 4; ++j)
                acc[i][j] = __builtin_amdgcn_mfma_f32_16x16x32_f16(af[i], bf[j], acc[i][j], 0, 0, 0);
    }
    // all gld_lds drained by last main-loop __syncthreads before compute.

    if (MODE == 0) {
        _Float16* tr = (_Float16*)smem;
#pragma unroll
        for (int pass = 0; pass < 2; ++pass) {
            bar_lgkm();
            if (wm == pass * 64) {
#pragma unroll
                for (int i = 0; i < 4; ++i) {
#pragma unroll
                    for (int v = 0; v < 4; ++v) {
                        const int lr = i * 16 + l4 + v;
                        const float* brow = bias;
                        if (gbid) {
                            int m = p * 128 + pass * 64 + lr;
                            if (m >= M) m = M - 1;
                            brow = bias + (size_t)clampi(gbid[m], BB) * ldbias;
                        }
#pragma unroll
                        for (int j = 0; j < 4; ++j) {
                            const int cc = wn + j * 16 + l15;
                            float val = acc[i][j][v] + brow[c * 128 + cc];
                            if (relu) val = fmaxf(val, 0.f);
                            tr[lr * 132 + cc] = (_Float16)val;
                        }
                    }
                }
            }
            bar_lgkm();
#pragma unroll
            for (int it = 0; it < 4; ++it) {
                const int id = it * 256 + tid;
                const int r  = id & 63;
                const int cg = id >> 6;
                f16x4 lo = *(const f16x4*)(tr + r * 132 + cg * 8);
                f16x4 hi = *(const f16x4*)(tr + r * 132 + cg * 8 + 4);
                f16x8 v8;
#pragma unroll
                for (int t = 0; t < 4; ++t) { v8[t] = lo[t]; v8[t + 4] = hi[t]; }
                const int kti = ktOff + (c << 2) + (cg >> 2);
                const int gr  = pass * 64 + r;
                size_t o = (((size_t)p * KTo + kti) * 4 + (cg & 3)) * 1024 + (size_t)gr * 8;
                *(f16x8*)((_Float16*)C + o) = v8;
            }
        }
    } else if (MODE == 1) {
#pragma unroll
        for (int i = 0; i < 4; ++i) {
#pragma unroll
            for (int v = 0; v < 4; ++v) {
                const int m = p * 128 + wm + i * 16 + l4 + v;
                if (m >= M) continue;
                const float* brow = bias;
                if (gbid) brow = bias + (size_t)clampi(gbid[m], BB) * ldbias;
#pragma unroll
                for (int j = 0; j < 4; ++j) {
                    const int col = c * 128 + wn + j * 16 + l15;
                    float val = acc[i][j][v] + brow[col];
                    if (relu) val = fmaxf(val, 0.f);
                    ((float*)C)[(size_t)m * ldc + col] = val;
                }
            }
        }
    } else if (MODE == 2) {
        // fallback path only: fused coalesced scatter-add (atomic)
        float* trf = (float*)smem;   // [32][130] f32
#pragma unroll
        for (int pass = 0; pass < 4; ++pass) {
            bar_lgkm();
            if (wm == ((pass >> 1) << 6)) {
                const int i0 = (pass & 1) << 1;
#pragma unroll
                for (int ii = 0; ii < 2; ++ii) {
                    const int i = i0 + ii;
                    const int lr = ii * 16 + l4;
#pragma unroll
                    for (int v = 0; v < 4; ++v) {
#pragma unroll
                        for (int j = 0; j < 4; ++j) {
                            const int cc = wn + j * 16 + l15;
                            float val = acc[i][j][v] + bias[c * 128 + cc];
                            if (relu) val = fmaxf(val, 0.f);
                            trf[(lr + v) * 130 + cc] = val;
                        }
                    }
                }
            }
            bar_lgkm();
            const int ebase = p * 128 + pass * 32;
#pragma unroll
            for (int it = 0; it < 16; ++it) {
                const int id = it * 256 + tid;
                const int lr = id >> 7;
                const int colg = id & 127;
                const int el = ebase + lr;
                if (el < M) {
                    const int node = clampi(srow[el], NN);
                    atomicAdd(&aux[(size_t)node * 512 + c * 128 + colg],
                              trf[lr * 130 + colg]);
                }
            }
        }
    } else if (MODE == 3) {
        const float* mw1 = aux;
        float* out = (float*)C;
#pragma unroll
        for (int i = 0; i < 4; ++i) {
#pragma unroll
            for (int v = 0; v < 4; ++v) {
                const int m = p * 128 + wm + i * 16 + l4 + v;
                const int mc = m < M ? m : M - 1;
                const float* brow = bias + (size_t)clampi(gbid[mc], BB) * ldbias;
                float s = 0.f;
#pragma unroll
                for (int j = 0; j < 4; ++j) {
                    const int col = c * 128 + wn + j * 16 + l15;
                    float val = acc[i][j][v] + brow[col];
                    val = fmaxf(val, 0.f);
                    s += val * mw1[col];
                }
                s += __shfl_down(s, 8, 16);
                s += __shfl_down(s, 4, 16);
                s += __shfl_down(s, 2, 16);
                s += __shfl_down(s, 1, 16);
                if (l15 == 0 && m < M) atomicAdd(&out[m], s);
            }
        }
    } else {
        // MODE 4: row-major f16 out (h_all). Same tr fill as MODE 0; write
        // rows: 16 lanes x 16B = 256B contiguous per row-tile.
        _Float16* tr = (_Float16*)smem;
        _Float16* hout = (_Float16*)C;
#pragma unroll
        for (int pass = 0; pass < 2; ++pass) {
            bar_lgkm();
            if (wm == pass * 64) {
#pragma unroll
                for (int i = 0; i < 4; ++i) {
#pragma unroll
                    for (int v = 0; v < 4; ++v) {
                        const int lr = i * 16 + l4 + v;
#pragma unroll
                        for (int j = 0; j < 4; ++j) {
                            const int cc = wn + j * 16 + l15;
                            float val = acc[i][j][v] + bias[c * 128 + cc];
                            if (relu) val = fmaxf(val, 0.f);
                            tr[lr * 132 + cc] = (_Float16)val;
                        }
                    }
                }
            }
            bar_lgkm();
#pragma unroll
            for (int it = 0; it < 4; ++it) {
                const int id = it * 256 + tid;
                const int cg = id & 15;            // col group of 8
                const int r  = (id >> 4) & 63;
                f16x4 lo = *(const f16x4*)(tr + r * 132 + cg * 8);
                f16x4 hi = *(const f16x4*)(tr + r * 132 + cg * 8 + 4);
                f16x8 v8;
#pragma unroll
                for (int t = 0; t < 4; ++t) { v8[t] = lo[t]; v8[t + 4] = hi[t]; }
                const size_t grow = (size_t)p * 128 + pass * 64 + r;
                *(f16x8*)(hout + grow * 512 + c * 128 + cg * 8) = v8;
            }
        }
    }
}

// ------------------------- helper kernels ----------------------------------

// fp32 -> blocked f16 [N/128][Kd/32].
__global__ void k_w2h_blk(const float* __restrict__ src, _Float16* __restrict__ dst,
                          int N, int Ksrc, int Kd, int mode)
{
    int t = blockIdx.x * blockDim.x + threadIdx.x;
    if (t >= N * Kd) return;
    int n = t / Kd, k = t - n * Kd;
    float v = 0.f;
    if (mode == 0)      { if (k < Ksrc) v = src[(size_t)n * Ksrc + k]; }
    else if (mode == 1) { if (k < 19) v = src[(size_t)n * 275 + k]; }
    else if (mode == 2) { if (k < 9) v = src[(size_t)n * Ksrc + k];
                          else if (k >= 32 && k < 544) v = src[(size_t)n * Ksrc + 9 + (k - 32)]; }
    else if (mode == 4) { if (k < Ksrc) v = src[(size_t)k * N + n]; }
    else                { v = src[(size_t)n * Ksrc + 9 + k]; }
    int KT = Kd >> 5;
    int nt = n >> 7, r = n & 127, kt = k >> 5, kg = (k >> 3) & 3, ko = k & 7;
    dst[(((size_t)nt * KT + kt) * 4 + kg) * 1024 + (size_t)r * 8 + ko] = (_Float16)v;
}

// whnc kt32 slot
__global__ void k_fill_w32(const float* __restrict__ nw0, _Float16* __restrict__ whnc)
{
    int t = blockIdx.x * blockDim.x + threadIdx.x;
    if (t >= 512 * 32) return;
    int n = t >> 5, k = t & 31;
    float v = (k < 9) ? nw0[(size_t)n * 521 + k] : 0.f;
    int nt = n >> 7, r = n & 127, kg = (k >> 3) & 3, ko = k & 7;
    whnc[(((size_t)nt * 33 + 32) * 4 + kg) * 1024 + (size_t)r * 8 + ko] = (_Float16)v;
}

// bfused[n] = dot(nw0[n][9:521], eb4) + nb0[n]
__global__ void k_bfuse(const float* __restrict__ nw0, const float* __restrict__ eb4,
                        const float* __restrict__ nb0, float* __restrict__ bf)
{
    int wave = (blockIdx.x * 256 + threadIdx.x) >> 6;
    int lane = threadIdx.x & 63;
    if (wave >= 512) return;
    const float* wr = nw0 + (size_t)wave * 521 + 9;
    float s = 0.f;
#pragma unroll
    for (int i = 0; i < 8; ++i) s += wr[lane * 8 + i] * eb4[lane * 8 + i];
    for (int off = 32; off; off >>= 1) s += __shfl_down(s, off);
    if (lane == 0) bf[wave] = s + nb0[wave];
}

// u_r[16,256] fp32
__global__ void k_u_r(const float* __restrict__ u, const float* __restrict__ w_sel,
                      const float* __restrict__ b_sel, float* __restrict__ u_r)
{
    int wave = (blockIdx.x * 256 + threadIdx.x) >> 6;
    int lane = threadIdx.x & 63;
    int b = wave >> 8, n = wave & 255;
    const float4* u4 = (const float4*)(u + (size_t)b * 4096);
    const float4* w4 = (const float4*)(w_sel + (size_t)n * 4096);
    float s = 0.f;
    for (int i = lane; i < 1024; i += 64) {
        float4 a = u4[i], c = w4[i];
        s += a.x * c.x + a.y * c.y + a.z * c.z + a.w * c.w;
    }
    for (int off = 32; off; off >>= 1) s += __shfl_down(s, off);
    if (lane == 0) u_r[b * 256 + n] = s + b_sel[n];
}

// ub[16][Nout] = u_r @ w[:, koff:koff+256]^T + b
__global__ void k_graph_bias(const float* __restrict__ u_r, const float* __restrict__ w,
                             const float* __restrict__ b, float* __restrict__ ub,
                             int Nout, int Ksrc, int koff)
{
    int wave = (blockIdx.x * 256 + threadIdx.x) >> 6;
    int lane = threadIdx.x & 63;
    if (wave >= 16 * Nout) return;
    int g = wave / Nout, n = wave - g * Nout;
    const float* ur = u_r + (size_t)g * 256;
    const float* wr = w + (size_t)n * Ksrc + koff;
    float s = 0.f;
#pragma unroll
    for (int i = 0; i < 4; ++i) s += ur[lane * 4 + i] * wr[lane * 4 + i];
    for (int off = 32; off; off >>= 1) s += __shfl_down(s, off);
    if (lane == 0) ub[(size_t)g * Nout + n] = s + b[n];
}

// gbe + per-node edge count in one pass
__global__ void k_gbe(const int* __restrict__ row, const int* __restrict__ batch,
                      int* __restrict__ gbe, float* __restrict__ cnt)
{
    int e = blockIdx.x * blockDim.x + threadIdx.x;
    if (e >= EE) return;
    int r = clampi(row[e], NN);
    gbe[e] = clampi(batch[r], BB);
    atomicAdd(&cnt[r], 1.f);
}

// out[n] = mb1[0]
__global__ void k_init_out(float* __restrict__ out, const float* __restrict__ mb1)
{
    int t = blockIdx.x * blockDim.x + threadIdx.x;
    if (t < NN) out[t] = mb1[0];
}

// CSR: exclusive prefix sum of (int)cnt over NN nodes. 1 block x 1024 thr.
__global__ void k_scan(const float* __restrict__ cnt, int* __restrict__ ptr,
                       int* __restrict__ cur)
{
    __shared__ int part[1024];
    const int t = threadIdx.x;
    const int PER = (NN + 1023) / 1024;   // 20
    const int base = t * PER;
    int s = 0;
    for (int i = 0; i < PER; ++i) {
        int n = base + i;
        if (n < NN) s += (int)cnt[n];
    }
    part[t] = s;
    __syncthreads();
    for (int off = 1; off < 1024; off <<= 1) {
        int v = (t >= off) ? part[t - off] : 0;
        __syncthreads();
        part[t] += v;
        __syncthreads();
    }
    int run = (t == 0) ? 0 : part[t - 1];
    for (int i = 0; i < PER; ++i) {
        int n = base + i;
        if (n < NN) {
            ptr[n] = run;
            cur[n] = run;
            run += (int)cnt[n];
        }
    }
    if (t == 1023) ptr[NN] = part[1023];
}

// CSR fill: place edge ids into per-node lists
__global__ void k_csr_fill(const int* __restrict__ row, int* __restrict__ cur,
                           int* __restrict__ idx)
{
    int e = blockIdx.x * blockDim.x + threadIdx.x;
    if (e >= EE) return;
    int r = clampi(row[e], NN);
    int pos = atomicAdd(&cur[r], 1);
    idx[pos] = e;
}

// CSR gather + mean + m_in write (block per node, thread per 2 cols).
// Index tile prefetched to LDS (breaks serial idx->h dependency).
__global__ void k_gather_csr(const float* __restrict__ x, const _Float16* __restrict__ h,
                             const int* __restrict__ ptr, const int* __restrict__ idx,
                             const float* __restrict__ cnt, _Float16* __restrict__ dst)
{
    __shared__ int eidx[256];
    const int n = blockIdx.x;
    const int t = threadIdx.x;
    const int base = ptr[n];
    const int deg = (int)cnt[n];
    const int c0 = 2 * t;
    float s0 = 0.f, s1 = 0.f;
    for (int d0 = 0; d0 < deg; d0 += 256) {
        int mdeg = deg - d0; if (mdeg > 256) mdeg = 256;
        if (t < mdeg) eidx[t] = idx[base + d0 + t];
        __syncthreads();
        for (int d = 0; d < mdeg; ++d) {
            const int e = eidx[d];
            f16x2 hv = *(const f16x2*)(h + (size_t)e * 512 + c0);
            s0 += (float)hv[0];
            s1 += (float)hv[1];
        }
        __syncthreads();
    }
    const float inv = 1.f / fmaxf(cnt[n], 1.f);
    const int mt = n >> 7, r = n & 127;
    const int kt = 1 + (c0 >> 5), kg = (c0 >> 3) & 3, ko = c0 & 7;
    _Float16* dp = dst + (((size_t)mt * 17 + kt) * 4 + kg) * 1024 + (size_t)r * 8 + ko;
    f16x2 o; o[0] = (_Float16)(s0 * inv); o[1] = (_Float16)(s1 * inv);
    *(f16x2*)dp = o;
    if (t < 16) {
        const int cx = 2 * t;
        f16x2 vx;
        vx[0] = (_Float16)(cx < 9 ? x[(size_t)n * 9 + cx] : 0.f);
        vx[1] = (_Float16)(cx + 1 < 9 ? x[(size_t)n * 9 + cx + 1] : 0.f);
        const int kg0 = (cx >> 3) & 3, ko0 = cx & 7;
        _Float16* d0 = dst + ((size_t)mt * 17 * 4 + kg0) * 1024 + (size_t)r * 8 + ko0;
        *(f16x2*)d0 = vx;
    }
}

// edge gather (unchanged)
__global__ void k_gather_edge_blk(const float* __restrict__ x, const float* __restrict__ ea,
                                  const int* __restrict__ row, const int* __restrict__ col,
                                  _Float16* __restrict__ dst, _Float16* __restrict__ pong,
                                  int e0, int ec, int MTR)
{
    int t = blockIdx.x * blockDim.x + threadIdx.x;
    if (t >= MTR * 4) return;
    int r = t >> 2, kg = t & 3;
    int e = e0 + r; int emax = e0 + ec - 1;
    if (e > emax) e = emax;
    int ri = clampi(row[e], NN), ci = clampi(col[e], NN);
    f16x8 v;
    f16x8 vx = (f16x8)(_Float16)0.f;
#pragma unroll
    for (int j = 0; j < 8; ++j) {
        int cc = kg * 8 + j;
        float fv = 0.f;
        if (cc < 9)       fv = x[(size_t)ri * 9 + cc];
        else if (cc < 18) fv = x[(size_t)ci * 9 + (cc - 9)];
        else if (cc == 18) fv = ea[e];
        v[j] = (_Float16)fv;
        if (cc < 9) vx[j] = (_Float16)x[(size_t)ci * 9 + cc];
    }
    *(f16x8*)(dst + (size_t)(r >> 7) * 4096 + (size_t)kg * 1024 + (size_t)(r & 127) * 8) = v;
    *(f16x8*)(pong + (((size_t)(r >> 7) * 33 + 32) * 4 + kg) * 1024 + (size_t)(r & 127) * 8) = vx;
}

// m_in gather from agg (fallback path only)
__global__ void k_gather_min(const float* __restrict__ x, const float* __restrict__ agg,
                             const float* __restrict__ cnt, _Float16* __restrict__ dst, int MTR)
{
    int t = blockIdx.x * blockDim.x + threadIdx.x;
    if (t >= MTR * 68) return;
    int r = t / 68, q = t - r * 68;
    int kt = q >> 2, kg = q & 3;
    int n = r < NN ? r : NN - 1;
    f16x8 v = (f16x8)(_Float16)0.f;
    if (kt == 0) {
#pragma unroll
        for (int j = 0; j < 8; ++j) {
            int cc = kg * 8 + j;
            if (cc < 9) v[j] = (_Float16)x[(size_t)n * 9 + cc];
        }
    } else {
        float inv = 1.f / fmaxf(cnt[n], 1.f);
        int cbase = (kt - 1) * 32 + kg * 8;
        const float4* ap = (const float4*)(agg + (size_t)n * 512 + cbase);
        float4 a0 = ap[0], a1 = ap[1];
        v[0] = (_Float16)(a0.x * inv); v[1] = (_Float16)(a0.y * inv);
        v[2] = (_Float16)(a0.z * inv); v[3] = (_Float16)(a0.w * inv);
        v[4] = (_Float16)(a1.x * inv); v[5] = (_Float16)(a1.y * inv);
        v[6] = (_Float16)(a1.z * inv); v[7] = (_Float16)(a1.w * inv);
    }
    *(f16x8*)(dst + ((size_t)(r >> 7) * 17 + kt) * 4096 + (size_t)kg * 1024 + (size_t)(r & 127) * 8) = v;
}

// ------------------------------- host --------------------------------------

#define GRID1(n) dim3(((n) + 255) / 256)

static inline void gemmB0(hipStream_t s, const _Float16* A, const _Float16* Wt, int KT, int KTs,
                          const float* bias, int ldbias, const int* gbid,
                          void* C, int KTo, int ktOff,
                          int M, int MT, int NT, int relu)
{
    hipLaunchKernelGGL(gemm_blk<0>, dim3(NT, MT), dim3(256), 0, s,
                       A, Wt, KT, KTs, bias, ldbias, gbid, C, KTo, ktOff, 0,
                       nullptr, nullptr, M, relu);
}
static inline void gemmB2(hipStream_t s, const _Float16* A, const _Float16* Wt, int KT, int KTs,
                          const float* bias, const int* srow, float* agg,
                          int M, int MT, int NT, int relu)
{
    hipLaunchKernelGGL(gemm_blk<2>, dim3(NT, MT), dim3(256), 0, s,
                       A, Wt, KT, KTs, bias, 0, nullptr, nullptr, 0, 0, 0,
                       srow, agg, M, relu);
}
static inline void gemmB3(hipStream_t s, const _Float16* A, const _Float16* Wt, int KT, int KTs,
                          const float* bias, int ldbias, const int* gbid,
                          float* out, const float* mw1,
                          int M, int MT, int NT)
{
    hipLaunchKernelGGL(gemm_blk<3>, dim3(NT, MT), dim3(256), 0, s,
                       A, Wt, KT, KTs, bias, ldbias, gbid, out, 0, 0, 0,
                       nullptr, (float*)mw1, M, 1);
}
static inline void gemmB4(hipStream_t s, const _Float16* A, const _Float16* Wt, int KT, int KTs,
                          const float* bias, _Float16* hout, int M, int MT, int NT)
{
    hipLaunchKernelGGL(gemm_blk<4>, dim3(NT, MT), dim3(256), 0, s,
                       A, Wt, KT, KTs, bias, 0, nullptr, hout, 0, 0, 0,
                       nullptr, nullptr, M, 1);
}

extern "C" void kernel_launch(void* const* d_in, const int* in_sizes, int n_in,
                              void* d_out, int out_size, void* d_ws, size_t ws_size,
                              hipStream_t stream)
{
    const float* x     = (const float*)d_in[0];
    const int*   ei    = (const int*)d_in[1];
    const float* ea    = (const float*)d_in[2];
    const float* u     = (const float*)d_in[3];
    const int*   batch = (const int*)d_in[4];
    const float* w_sel = (const float*)d_in[5];
    const float* b_sel = (const float*)d_in[6];
    const float* ew0 = (const float*)d_in[7];   const float* eb0 = (const float*)d_in[8];
    const float* ew1 = (const float*)d_in[9];   const float* eb1 = (const float*)d_in[10];
    const float* ew2 = (const float*)d_in[11];  const float* eb2 = (const float*)d_in[12];
    const float* ew3 = (const float*)d_in[13];  const float* eb3 = (const float*)d_in[14];
    const float* ew4 = (const float*)d_in[15];  const float* eb4 = (const float*)d_in[16];
    const float* nw0 = (const float*)d_in[17];  const float* nb0 = (const float*)d_in[18];
    const float* nw1 = (const float*)d_in[19];  const float* nb1 = (const float*)d_in[20];
    const float* mw0 = (const float*)d_in[21];  const float* mb0 = (const float*)d_in[22];
    const float* mw1 = (const float*)d_in[23];  const float* mb1 = (const float*)d_in[24];

    const int* row = ei;
    const int* col = ei + EE;

    const int MTm = (NN + 127) / 128;           // 157
    const size_t EEp = 100352;                  // 784*128 >= EE padded rows

    // ---- size planning (pure fn of ws_size -> capture-safe) ----
    auto alsz = [](size_t b) { return (b + 255) & ~(size_t)255; };
    const size_t commonB =
        alsz(20000 * 4) + alsz(1024 * 4) + alsz(16 * 256 * 4) + alsz(16 * 1024 * 4) +
        alsz(16 * 512 * 4) + alsz(512 * 4) + alsz((size_t)EE * 4) +
        alsz((size_t)8 * 4096 * 2) + 3 * alsz((size_t)8 * 32 * 4096 * 2) +
        alsz((size_t)4 * 33 * 4096 * 2) + alsz((size_t)4 * 16 * 4096 * 2) +
        alsz((size_t)4 * 17 * 4096 * 2) + alsz((size_t)4 * 16 * 4096 * 2) +
        alsz((size_t)8 * 16 * 4096 * 2) + alsz((size_t)MTm * 17 * 4096 * 2);
    const size_t aggB = alsz((size_t)NN * 512 * 4);
    const size_t csrB = alsz((NN + 2) * 4) + alsz((size_t)NN * 4) +
                        alsz((size_t)EE * 4) + alsz(EEp * 512 * 2);
    auto chB = [&](int ec) {
        size_t Mr = (size_t)((ec + 255) / 256) * 256;
        return alsz(Mr * 64) + 2 * alsz(Mr * 2112);
    };
    // CSR path at EC=16384: ~206MB total (fits where the 214MB fallback fit)
    const bool csrPath = (commonB + csrB + chB(16384) + 8192 <= ws_size);
    int EC = 5000;
    if (csrPath) EC = 16384;
    else {
        static const int ecOpts[] = {32768, 25000, 12500, 10000, 5000};
        for (int i = 0; i < 5; ++i) {
            if (commonB + aggB + chB(ecOpts[i]) + 8192 <= ws_size) { EC = ecOpts[i]; break; }
        }
    }
    const bool big = (EC >= 16384);

    // ---- allocation ----
    char* W = (char*)d_ws;
    size_t off = 0;
    auto alloc = [&](size_t bytes) -> char* {
        char* p = W + off;
        off = (off + bytes + 255) & ~(size_t)255;
        return p;
    };
    float* cnt = (float*)alloc(20000 * 4);
    float* agg = nullptr;
    if (!csrPath) agg = (float*)alloc((size_t)NN * 512 * 4);
    float* zbias = (float*)alloc(1024 * 4);             // stays zero
    const size_t zeroBytes = off;
    float*    u_r  = (float*)alloc(16 * 256 * 4);
    float*    ub0  = (float*)alloc(16 * 1024 * 4);
    float*    ubm  = (float*)alloc(16 * 512 * 4);
    float*    bfu  = (float*)alloc(512 * 4);
    int*      gbe  = (int*)alloc((size_t)EE * 4);
    _Float16* wh0   = (_Float16*)alloc((size_t)8 * 1 * 4096 * 2);
    _Float16* wh1   = (_Float16*)alloc((size_t)8 * 32 * 4096 * 2);
    _Float16* wh2   = (_Float16*)alloc((size_t)8 * 32 * 4096 * 2);
    _Float16* wh3   = (_Float16*)alloc((size_t)8 * 32 * 4096 * 2);
    _Float16* whnc  = (_Float16*)alloc((size_t)4 * 33 * 4096 * 2);
    _Float16* whn1  = (_Float16*)alloc((size_t)4 * 16 * 4096 * 2);
    _Float16* whm0  = (_Float16*)alloc((size_t)4 * 17 * 4096 * 2);
    _Float16* nw0eoB= (_Float16*)alloc((size_t)4 * 16 * 4096 * 2);
    _Float16* ew4T  = (_Float16*)alloc((size_t)8 * 16 * 4096 * 2);
    _Float16* m_in  = (_Float16*)alloc((size_t)MTm * 17 * 4096 * 2);
    int*      csr_ptr = nullptr; int* csr_cur = nullptr; int* csr_idx = nullptr;
    _Float16* h_all = nullptr;
    if (csrPath) {
        csr_ptr = (int*)alloc((NN + 2) * 4);
        csr_cur = (int*)alloc((size_t)NN * 4);
        csr_idx = (int*)alloc((size_t)EE * 4);
        h_all   = (_Float16*)alloc(EEp * 512 * 2);
    }
    const size_t MTR = (size_t)((EC + 255) / 256) * 256;
    _Float16* e_in = (_Float16*)alloc(MTR * 64);
    _Float16* ping = (_Float16*)alloc(MTR * 2112);
    _Float16* pong = (_Float16*)alloc(MTR * 2112);
    const int NCH = (EE + EC - 1) / EC;

    (void)hipMemsetAsync(W, 0, zeroBytes, stream);
    hipLaunchKernelGGL(k_init_out, GRID1(NN), dim3(256), 0, stream, (float*)d_out, mb1);

    hipLaunchKernelGGL(k_u_r, dim3(1024), dim3(256), 0, stream, u, w_sel, b_sel, u_r);
    hipLaunchKernelGGL(k_graph_bias, GRID1(16 * 1024 * 64), dim3(256), 0, stream,
                       u_r, ew0, eb0, ub0, 1024, 275, 19);
    hipLaunchKernelGGL(k_graph_bias, GRID1(16 * 512 * 64), dim3(256), 0, stream,
                       u_r, mw0, mb0, ubm, 512, 777, 521);
    hipLaunchKernelGGL(k_gbe, GRID1(EE), dim3(256), 0, stream, row, batch, gbe, cnt);
    hipLaunchKernelGGL(k_bfuse, dim3(128), dim3(256), 0, stream, nw0, eb4, nb0, bfu);
    if (csrPath) {
        hipLaunchKernelGGL(k_scan, dim3(1), dim3(1024), 0, stream, cnt, csr_ptr, csr_cur);
        hipLaunchKernelGGL(k_csr_fill, GRID1(EE), dim3(256), 0, stream, row, csr_cur, csr_idx);
    }

    auto pack = [&](const float* w, _Float16* wh, int N, int Ksrc, int Kd, int mode) {
        hipLaunchKernelGGL(k_w2h_blk, GRID1(N * Kd), dim3(256), 0, stream, w, wh, N, Ksrc, Kd, mode);
    };
    pack(ew0, wh0, 1024, 275, 32, 1);
    pack(ew1, wh1, 1024, 1024, 1024, 0);
    pack(ew2, wh2, 1024, 1024, 1024, 0);
    pack(ew3, wh3, 1024, 1024, 1024, 0);
    pack(nw1, whn1, 512, 512, 512, 0);
    pack(mw0, whm0, 512, 777, 544, 2);
    pack(nw0, nw0eoB, 512, 521, 512, 5);
    pack(ew4, ew4T, 1024, 512, 512, 4);
    // W_comb = nw0eo @ ew4 -> whnc kt 0..31 (blocked out)
    gemmB0(stream, nw0eoB, ew4T, 16, 16, zbias, 0, nullptr, whnc, 33, 0, 512, 4, 8, 0);
    hipLaunchKernelGGL(k_fill_w32, GRID1(512 * 32), dim3(256), 0, stream, nw0, whnc);

    for (int ch = 0; ch < NCH; ++ch) {
        int e0 = ch * EC;
        int ec = EC; if (e0 + ec > EE) ec = EE - e0;
        const int ecr  = ((ec + 255) / 256) * 256;
        const int MTc  = ecr / 128;
        const int MT2c = ecr / 256;
        hipLaunchKernelGGL(k_gather_edge_blk, GRID1(ecr * 4), dim3(256), 0, stream,
                           x, ea, row, col, e_in, pong, e0, ec, ecr);
        gemmB0(stream, e_in, wh0, 1, 1, ub0, 1024, gbe + e0, ping, 33, 0, ec, MTc, 8, 1);
        auto wideL = [&](const _Float16* Ain, const _Float16* Wt,
                         const float* b, _Float16* Cout) {
            if (big)
                hipLaunchKernelGGL(gemm256h, dim3(8, MT2c), dim3(256), 0, stream,
                                   Ain, Wt, 32, 33, b, Cout, 33, 0);
            else
                hipLaunchKernelGGL(gemmAD, dim3(8, MTc), dim3(256), 0, stream,
                                   Ain, Wt, 32, 33, b, Cout, 33, 0);
        };
        wideL(ping, wh1, eb1, pong);
        wideL(pong, wh2, eb2, ping);
        wideL(ping, wh3, eb3, pong);
        // nc: fused (ew4+nw0) GEMM, K=1056, KT=33 (odd tail in gemmAD)
        hipLaunchKernelGGL(gemmAD, dim3(4, MTc), dim3(256), 0, stream,
                           pong, whnc, 33, 33, bfu, ping, 16, 0);
        // n1
        if (csrPath)
            gemmB4(stream, ping, whn1, 16, 16, nb1, h_all + (size_t)e0 * 512, ec, MTc, 4);
        else
            gemmB2(stream, ping, whn1, 16, 16, nb1, row + e0, agg, ec, MTc, 4, 1);
    }

    if (csrPath) {
        hipLaunchKernelGGL(k_gather_csr, dim3(NN), dim3(256), 0, stream,
                           x, h_all, csr_ptr, csr_idx, cnt, m_in);
    } else {
        hipLaunchKernelGGL(k_gather_min, GRID1((int)(MTm * 128) * 68), dim3(256), 0, stream,
                           x, agg, cnt, m_in, MTm * 128);
    }
    // m0 + final fused (mode 3)
    gemmB3(stream, m_in, whm0, 17, 17, ubm, 512, batch, (float*)d_out, mw1, NN, MTm, 4);
}